// Round 5
// baseline (407.884 us; speedup 1.0000x reference)
//
#include <hip/hip_runtime.h>
#include <math.h>

typedef unsigned short u16;
typedef unsigned int u32;
typedef __attribute__((ext_vector_type(8))) short short8;
typedef __attribute__((ext_vector_type(4))) float f32x4;

__device__ inline u16 f2b(float f) {
  u32 u = __builtin_bit_cast(u32, f);
  u32 r = u + 0x7fffu + ((u >> 16) & 1u);
  return (u16)(r >> 16);
}
__device__ inline float b2f(u16 b) {
  return __builtin_bit_cast(float, (u32)b << 16);
}
__device__ inline u32 pk2(float a, float b) {
  return (u32)f2b(a) | ((u32)f2b(b) << 16);
}
__device__ inline float eluf(float x) { return x > 0.f ? x : expf(x) - 1.f; }

__device__ inline f32x4 mfma16(short8 a, short8 b, f32x4 c) {
  return __builtin_amdgcn_mfma_f32_16x16x32_bf16(a, b, c, 0, 0, 0);
}
__device__ inline void gload16(const u16* g, u16* l) {
  __builtin_amdgcn_global_load_lds((__attribute__((address_space(1))) void*)(g),
                                   (__attribute__((address_space(3))) void*)(l),
                                   16, 0, 0);
}

// ---------------------------------------------------------------------------
// prep: A_pe[s][d] = PE[s][d] + emb_b[d]  (bf16)   and pb_bias[12][512] gather
// ---------------------------------------------------------------------------
__global__ __launch_bounds__(256) void prep_pe(
    const float* __restrict__ emb_b, const float* __restrict__ bq,
    const float* __restrict__ bk, const float* __restrict__ bv,
    u16* __restrict__ A_pe, float* __restrict__ pb_bias) {
  int bid = blockIdx.x, t = threadIdx.x;
  if (bid < 512) {
    int s = bid;
    float div = expf((2.f * t) * (-9.210340371976184f / 512.f));
    float arg = (float)s * div;
    A_pe[s * 512 + 2 * t] = f2b(sinf(arg) + emb_b[2 * t]);
    A_pe[s * 512 + 2 * t + 1] = f2b(cosf(arg) + emb_b[2 * t + 1]);
  } else {
    int i = (bid - 512) * 256 + t;  // 0..6143
    int z = i >> 9, e = i & 511;
    int ty = z >> 2, m = z & 3;
    const float* bp = (ty == 0) ? bq : (ty == 1) ? bk : bv;
    pb_bias[i] = bp[m * 512 + e];
  }
}

// ---------------------------------------------------------------------------
// transpose the 12 QKV weight matrices (fp32 DMxDM, row d, col e) -> bf16 [e][d]
// ---------------------------------------------------------------------------
__global__ __launch_bounds__(256) void transw(
    const float* __restrict__ Wq, const float* __restrict__ Wk,
    const float* __restrict__ Wv, u16* __restrict__ WTqkv) {
  __shared__ float tile[64][65];
  int mid = blockIdx.x;
  const float* W = ((mid < 4) ? Wq : (mid < 8) ? Wk : Wv) + (long)(mid & 3) * 262144;
  u16* WT = WTqkv + (long)mid * 262144;
  int d0 = blockIdx.y * 64, e0 = blockIdx.z * 64;
  int t = threadIdx.x;
  int dr = t >> 2, ec = (t & 3) * 16;
#pragma unroll
  for (int j = 0; j < 16; j += 4) {
    float4 v = *(const float4*)&W[(long)(d0 + dr) * 512 + e0 + ec + j];
    tile[dr][ec + j] = v.x;
    tile[dr][ec + j + 1] = v.y;
    tile[dr][ec + j + 2] = v.z;
    tile[dr][ec + j + 3] = v.w;
  }
  __syncthreads();
  int er = t >> 2, dc = (t & 3) * 16;
  u16 tmp[16] __attribute__((aligned(16)));
#pragma unroll
  for (int j = 0; j < 16; ++j) tmp[j] = f2b(tile[dc + j][er]);
  *(short8*)&WT[(long)(e0 + er) * 512 + d0 + dc] = *(short8*)&tmp[0];
  *(short8*)&WT[(long)(e0 + er) * 512 + d0 + dc + 8] = *(short8*)&tmp[8];
}

// ---------------------------------------------------------------------------
// EW[z][f][e] = sum_d emb_W[f][d] * W_z[d][e]  — single pass over W per z
// ---------------------------------------------------------------------------
__global__ __launch_bounds__(256) void ew_kernel(
    const float* __restrict__ Wq, const float* __restrict__ Wk,
    const float* __restrict__ Wv, const float* __restrict__ embW,
    float* __restrict__ EW) {
  __shared__ float eb[4][512];
  int z = blockIdx.x;
  const float* W = ((z < 4) ? Wq : (z < 8) ? Wk : Wv) + (long)(z & 3) * 262144;
  int t = threadIdx.x;
#pragma unroll
  for (int i = 0; i < 8; ++i) eb[0][t + i * 256] = embW[t + i * 256];
  __syncthreads();
  float a[4][2] = {};
  for (int d = 0; d < 512; ++d) {
    float w0 = W[(long)d * 512 + t];
    float w1v = W[(long)d * 512 + t + 256];
#pragma unroll
    for (int f = 0; f < 4; ++f) {
      float e = eb[f][d];
      a[f][0] += e * w0;
      a[f][1] += e * w1v;
    }
  }
#pragma unroll
  for (int f = 0; f < 4; ++f) {
    EW[((long)z * 4 + f) * 512 + t] = a[f][0];
    EW[((long)z * 4 + f) * 512 + t + 256] = a[f][1];
  }
}

// ---------------------------------------------------------------------------
// WEFF_m[d][j] = sum_e Wo_m[d][e] * w1[o][m*512+e][k]   (j = o*3+k, 15 + pad)
// stored transposed: WEFFT[m][j][d] bf16.  Extra block computes bias_t.
// ---------------------------------------------------------------------------
__global__ __launch_bounds__(64) void weff_kernel(
    const float* __restrict__ Wo, const float* __restrict__ bo,
    const float* __restrict__ w1, u16* __restrict__ WEFFT,
    float* __restrict__ bias_t) {
  const int bid = blockIdx.x, l = threadIdx.x;
  if (bid < 2048) {
    int m = bid >> 9, d = bid & 511;
    const float* wrow = Wo + ((long)m * 512 + d) * 512;
    float a[15] = {};
#pragma unroll
    for (int i = 0; i < 8; ++i) {
      int e = l * 8 + i;
      float wv = wrow[e];
#pragma unroll
      for (int o = 0; o < 5; ++o)
#pragma unroll
        for (int k = 0; k < 3; ++k)
          a[o * 3 + k] += wv * w1[((long)o * 2048 + m * 512 + e) * 3 + k];
    }
#pragma unroll
    for (int j = 0; j < 15; ++j) {
      float v = a[j];
      for (int o = 1; o < 64; o <<= 1) v += __shfl_xor(v, o);
      if (l == 0) WEFFT[((long)m * 16 + j) * 512 + d] = f2b(v);
    }
    if (l == 0) WEFFT[((long)m * 16 + 15) * 512 + d] = 0;
  } else {
    float a[15] = {};
    for (int c = l; c < 2048; c += 64) {
      float bv = bo[c];
#pragma unroll
      for (int o = 0; o < 5; ++o)
#pragma unroll
        for (int k = 0; k < 3; ++k)
          a[o * 3 + k] += bv * w1[((long)o * 2048 + c) * 3 + k];
    }
#pragma unroll
    for (int j = 0; j < 15; ++j) {
      float v = a[j];
      for (int o = 1; o < 64; o <<= 1) v += __shfl_xor(v, o);
      if (l == 0) bias_t[j] = v;
    }
    if (l == 0) bias_t[15] = 0.f;
  }
}

// ---------------------------------------------------------------------------
// generic bf16 GEMM  C[r][c] = sum_k A[r][k] * BT[c][k] + bias[c]
// ---------------------------------------------------------------------------
template <bool OBF>
__global__ __launch_bounds__(256) void gemm_bt(
    const u16* __restrict__ A, long sAz, int lda, const u16* __restrict__ BT,
    const float* __restrict__ bias, void* __restrict__ out, long sOz, int ldo) {
  __shared__ u16 As[128 * 32];
  __shared__ u16 Bs[128 * 32];
  const int z = blockIdx.z;
  const int tid = threadIdx.x, w = tid >> 6, l = tid & 63;
  const long row0 = (long)blockIdx.y * 128;
  const u16* Ab = A + (long)z * sAz + row0 * lda;
  const u16* Bb = BT + (long)z * 262144 + (long)blockIdx.x * 128 * 512;
  const u16* ga = Ab + (long)(w * 32 + (l >> 2)) * lda + (l & 3) * 8;
  const u16* gb = Bb + (long)(w * 32 + (l >> 2)) * 512 + (l & 3) * 8;
  u16* lA = As + w * 32 * 32;
  u16* lB = Bs + w * 32 * 32;
  f32x4 acc[4][4] = {};
  const int wr = (w >> 1) * 64, wc = (w & 1) * 64;
  for (int kt = 0; kt < 16; ++kt) {
    gload16(ga + kt * 32, lA);
    gload16(ga + kt * 32 + 16 * lda, lA + 16 * 32);
    gload16(gb + kt * 32, lB);
    gload16(gb + kt * 32 + 16 * 512, lB + 16 * 32);
    __syncthreads();
    short8 af[4], bf[4];
#pragma unroll
    for (int i = 0; i < 4; ++i)
      af[i] = *(const short8*)&As[(wr + i * 16 + (l & 15)) * 32 + (l >> 4) * 8];
#pragma unroll
    for (int i = 0; i < 4; ++i)
      bf[i] = *(const short8*)&Bs[(wc + i * 16 + (l & 15)) * 32 + (l >> 4) * 8];
#pragma unroll
    for (int i = 0; i < 4; ++i)
#pragma unroll
      for (int j = 0; j < 4; ++j) acc[i][j] = mfma16(af[i], bf[j], acc[i][j]);
    __syncthreads();
  }
  const int colB = blockIdx.x * 128 + wc;
#pragma unroll
  for (int i = 0; i < 4; ++i)
#pragma unroll
    for (int j = 0; j < 4; ++j) {
      int col = colB + j * 16 + (l & 15);
      float bb = bias[(long)z * 512 + col];
#pragma unroll
      for (int q = 0; q < 4; ++q) {
        long r = row0 + wr + i * 16 + (l >> 4) * 4 + q;
        float v = acc[i][j][q] + bb;
        if (OBF)
          ((u16*)out)[(long)z * sOz + r * ldo + col] = f2b(v);
        else
          ((float*)out)[(long)z * sOz + r * ldo + col] = v;
      }
    }
}

// ---------------------------------------------------------------------------
// QKV generation: rank-4 update + PB table (bf16), fused per-head L2 norm.
// nm modules per launch; per-module output stride mstride (elements).
// ---------------------------------------------------------------------------
__global__ __launch_bounds__(256) void qkv_all(
    const float* __restrict__ x, const float* __restrict__ EW,
    const u16* __restrict__ PB, u16* __restrict__ Q, u16* __restrict__ K,
    u16* __restrict__ V, int m0, int nm, long mstride) {
  const int rid = blockIdx.x;  // b*512+s
  const int s = rid & 511;
  const int t = threadIdx.x;
  const float* xr = x + (long)rid * 7;
  const float x0 = xr[0], x1 = xr[1], x2 = xr[2];
  for (int mm = 0; mm < nm; ++mm) {
    const int m = m0 + mm;
    const float xd = xr[3 + m];
    const long obase = (long)mm * mstride + (long)rid * 512 + 2 * t;
    float2 res[3];
#pragma unroll
    for (int ty = 0; ty < 3; ++ty) {
      int z = ty * 4 + m;
      const float* ew = EW + (long)z * 4 * 512;
      float2 e0 = *(const float2*)&ew[0 * 512 + 2 * t];
      float2 e1 = *(const float2*)&ew[1 * 512 + 2 * t];
      float2 e2 = *(const float2*)&ew[2 * 512 + 2 * t];
      float2 e3 = *(const float2*)&ew[3 * 512 + 2 * t];
      u32 pb2 = *(const u32*)&PB[((long)z * 512 + s) * 512 + 2 * t];
      res[ty].x = xd * e0.x + x0 * e1.x + x1 * e2.x + x2 * e3.x + b2f((u16)pb2);
      res[ty].y =
          xd * e0.y + x0 * e1.y + x1 * e2.y + x2 * e3.y + b2f((u16)(pb2 >> 16));
    }
    *(u32*)&V[obase] = pk2(res[2].x, res[2].y);
#pragma unroll
    for (int ty = 0; ty < 2; ++ty) {
      float ss = res[ty].x * res[ty].x + res[ty].y * res[ty].y;
      for (int o = 1; o < 32; o <<= 1) ss += __shfl_xor(ss, o);
      float sc = 1.f / fmaxf(sqrtf(ss), 1e-12f);
      u16* P = ty ? K : Q;
      *(u32*)&P[obase] = pk2(res[ty].x * sc, res[ty].y * sc);
    }
  }
}

// ---------------------------------------------------------------------------
// V transpose: VT[(b*8+h)*64 + dk][s] = V[(b*512+s)][h*64+dk]; z = module
// ---------------------------------------------------------------------------
__global__ __launch_bounds__(256) void vtrans(const u16* __restrict__ Vg,
                                              u16* __restrict__ VTg,
                                              long mstride) {
  __shared__ u16 tile[64][72];
  const u16* V = Vg + (long)blockIdx.z * mstride;
  u16* VT = VTg + (long)blockIdx.z * mstride;
  int bh = blockIdx.x;
  int b = bh >> 3, h = bh & 7;
  int st = blockIdx.y;
  int t = threadIdx.x;
  int sr = t >> 2, kc = (t & 3) * 16;
  long gsrc = ((long)b * 512 + st * 64 + sr) * 512 + h * 64 + kc;
  *(short8*)&tile[sr][kc] = *(const short8*)&V[gsrc];
  *(short8*)&tile[sr][kc + 8] = *(const short8*)&V[gsrc + 8];
  __syncthreads();
  int kr = t >> 2, sc = (t & 3) * 16;
  u16 tmp[16] __attribute__((aligned(16)));
#pragma unroll
  for (int j = 0; j < 16; ++j) tmp[j] = tile[sc + j][kr];
  long gdst = ((long)bh * 64 + kr) * 512 + st * 64 + sc;
  *(short8*)&VT[gdst] = *(short8*)&tmp[0];
  *(short8*)&VT[gdst + 8] = *(short8*)&tmp[8];
}

// ---------------------------------------------------------------------------
// flash attention, max-free (Q,K L2-normed => |S|<=~1 => P=exp(S) directly).
// Double-buffered K/V via global_load_lds, XOR chunk swizzle, one barrier per
// KV tile, prefetch overlaps compute, row-sum via ones-MFMA. z = module.
// ---------------------------------------------------------------------------
__global__ __launch_bounds__(256) void attn_kernel(
    const u16* __restrict__ Qg, const u16* __restrict__ Kg,
    const u16* __restrict__ VTg, u16* __restrict__ ctxg, long mstride) {
  __shared__ u16 Kb[2][64][64];
  __shared__ u16 Vb[2][64][64];
  __shared__ u16 Ps[4][32][72];
  const u16* Q = Qg + (long)blockIdx.z * mstride;
  const u16* K = Kg + (long)blockIdx.z * mstride;
  const u16* VT = VTg + (long)blockIdx.z * mstride;
  u16* ctx = ctxg + (long)blockIdx.z * mstride;
  const int bh = blockIdx.x;  // b*8+h
  const int qb = blockIdx.y;
  const int b = bh >> 3, h = bh & 7;
  const int tid = threadIdx.x, w = tid >> 6, l = tid & 63;
  const long rowbase = (long)b * 512;
  const int hoff = h * 64;

  const int rw = l >> 3;         // row within 8-row stripe this lane fills
  const int gch = (l & 7) ^ rw;  // pre-swizzled global 16B-chunk index

  // Q fragments straight from global (L3-resident; one-time read)
  short8 qf[2][2];
#pragma unroll
  for (int rt = 0; rt < 2; ++rt)
#pragma unroll
    for (int kk = 0; kk < 2; ++kk)
      qf[rt][kk] = *(const short8*)&Q[(rowbase + qb * 128 + w * 32 + rt * 16 +
                                       (l & 15)) *
                                          512 +
                                      hoff + kk * 32 + (l >> 4) * 8];

  short8 ones;
#pragma unroll
  for (int i = 0; i < 8; ++i) ones[i] = (short)0x3F80;  // bf16 1.0

  f32x4 o_acc[2][4] = {};
  f32x4 l_acc[2] = {};

  const u16* Kgbase = K + rowbase * 512 + hoff + gch * 8;
  const u16* Vgbase = VT + (long)bh * 64 * 512 + gch * 8;

#define STAGE(bf, kt)                                                         \
  {                                                                           \
    _Pragma("unroll") for (int i = 0; i < 2; ++i) {                           \
      int rr = w * 16 + i * 8;                                                \
      gload16(Kgbase + (long)((kt)*64 + rr + rw) * 512, &Kb[bf][rr][0]);      \
      gload16(Vgbase + (long)(rr + rw) * 512 + (kt)*64, &Vb[bf][rr][0]);      \
    }                                                                         \
  }

  STAGE(0, 0);
  __syncthreads();

  for (int kt = 0; kt < 8; ++kt) {
    const int cur = kt & 1;
    if (kt < 7) STAGE(cur ^ 1, kt + 1);  // async prefetch, in flight
    // QK^T
    f32x4 s_acc[2][4] = {};
    __builtin_amdgcn_s_setprio(1);
#pragma unroll
    for (int kk = 0; kk < 2; ++kk) {
      short8 bfr[4];
#pragma unroll
      for (int nt = 0; nt < 4; ++nt) {
        int R = nt * 16 + (l & 15);
        int ch = ((kk << 2) + (l >> 4)) ^ (l & 7);
        bfr[nt] =
            *(const short8*)((const char*)&Kb[cur][0][0] + R * 128 + ch * 16);
      }
#pragma unroll
      for (int rt = 0; rt < 2; ++rt)
#pragma unroll
        for (int nt = 0; nt < 4; ++nt)
          s_acc[rt][nt] = mfma16(qf[rt][kk], bfr[nt], s_acc[rt][nt]);
    }
    __builtin_amdgcn_s_setprio(0);
    // P = exp(S), bounded by e; per-wave P tile (no cross-wave barrier)
#pragma unroll
    for (int rt = 0; rt < 2; ++rt)
#pragma unroll
      for (int nt = 0; nt < 4; ++nt)
#pragma unroll
        for (int q = 0; q < 4; ++q)
          Ps[w][rt * 16 + (l >> 4) * 4 + q][nt * 16 + (l & 15)] =
              f2b(__expf(s_acc[rt][nt][q]));
    // PV + row-sum via ones-MFMA
    __builtin_amdgcn_s_setprio(1);
#pragma unroll
    for (int kk = 0; kk < 2; ++kk) {
      short8 pa[2], vbf[4];
#pragma unroll
      for (int rt = 0; rt < 2; ++rt)
        pa[rt] =
            *(const short8*)&Ps[w][rt * 16 + (l & 15)][kk * 32 + (l >> 4) * 8];
#pragma unroll
      for (int dt = 0; dt < 4; ++dt) {
        int R = dt * 16 + (l & 15);
        int ch = ((kk << 2) + (l >> 4)) ^ (l & 7);
        vbf[dt] =
            *(const short8*)((const char*)&Vb[cur][0][0] + R * 128 + ch * 16);
      }
#pragma unroll
      for (int rt = 0; rt < 2; ++rt) {
        l_acc[rt] = mfma16(pa[rt], ones, l_acc[rt]);
#pragma unroll
        for (int dt = 0; dt < 4; ++dt)
          o_acc[rt][dt] = mfma16(pa[rt], vbf[dt], o_acc[rt][dt]);
      }
    }
    __builtin_amdgcn_s_setprio(0);
    __syncthreads();  // drains vmcnt (prefetch done) + frees cur for rewrite
  }
#undef STAGE
#pragma unroll
  for (int rt = 0; rt < 2; ++rt)
#pragma unroll
    for (int q = 0; q < 4; ++q) {
      float inv = 1.f / l_acc[rt][q];
      int r = qb * 128 + w * 32 + rt * 16 + (l >> 4) * 4 + q;
#pragma unroll
      for (int dt = 0; dt < 4; ++dt)
        ctx[(rowbase + r) * 512 + hoff + dt * 16 + (l & 15)] =
            f2b(o_acc[rt][dt][q] * inv);
    }
}

// ---------------------------------------------------------------------------
// t[r][j] = sum_m ctx_m[r][:] . WEFFT[m][j][:]   (r = b*512+s, j = o*3+k)
// ---------------------------------------------------------------------------
__global__ __launch_bounds__(64) void t_gemm(const u16* __restrict__ ctx4,
                                             const u16* __restrict__ WEFFT,
                                             float* __restrict__ t) {
  const int l = threadIdx.x;
  const long r0 = (long)blockIdx.x * 16;
  f32x4 acc = {};
#pragma unroll
  for (int m = 0; m < 4; ++m) {
    const u16* A =
        ctx4 + (long)m * 8388608 + (r0 + (l & 15)) * 512 + (l >> 4) * 8;
    const u16* Bb = WEFFT + m * 8192 + (l & 15) * 512 + (l >> 4) * 8;
#pragma unroll
    for (int kt = 0; kt < 16; ++kt) {
      short8 af = *(const short8*)(A + kt * 32);
      short8 bf = *(const short8*)(Bb + kt * 32);
      acc = mfma16(af, bf, acc);
    }
  }
#pragma unroll
  for (int q = 0; q < 4; ++q)
    t[(r0 + (l >> 4) * 4 + q) * 16 + (l & 15)] = acc[q];
}

// ---------------------------------------------------------------------------
// tail: c1 (from t) + elu -> conv2 + elu + pool -> fc1/fc2/fc3 + LayerNorm
// one block per batch element, everything in LDS
// ---------------------------------------------------------------------------
__global__ __launch_bounds__(256) void tail_kernel(
    const float* __restrict__ t, const float* __restrict__ bias_t,
    const float* __restrict__ b1, const float* __restrict__ w2,
    const float* __restrict__ b2, const float* __restrict__ fw1,
    const float* __restrict__ fb1, const float* __restrict__ fw2,
    const float* __restrict__ fb2, const float* __restrict__ fw3,
    const float* __restrict__ fb3, const float* __restrict__ g,
    const float* __restrict__ be, float* __restrict__ out) {
  __shared__ float ts[512][16];
  __shared__ float c1s[5][512];
  __shared__ float flat[512];
  __shared__ float z1[256], z2[128], z3[96];
  int b = blockIdx.x, tid = threadIdx.x;
  const float4* tsrc = (const float4*)(t + (long)b * 8192);
  float4* tdst = (float4*)&ts[0][0];
#pragma unroll
  for (int i = 0; i < 8; ++i) tdst[tid + i * 256] = tsrc[tid + i * 256];
  __syncthreads();
#pragma unroll
  for (int i = 0; i < 10; ++i) {
    int idx = tid + i * 256;  // 0..2559
    int o = idx >> 9, s = idx & 511;
    float a = b1[o];
#pragma unroll
    for (int k = 0; k < 3; ++k) {
      int ss = s + k - 1;
      if (ss >= 0 && ss < 512) a += ts[ss][o * 3 + k] + bias_t[o * 3 + k];
    }
    c1s[o][s] = eluf(a);
  }
  __syncthreads();
#pragma unroll
  for (int i = 0; i < 2; ++i) {
    int r = tid + i * 256;  // 0..511
    int o = r >> 8, sp = r & 255;
    float mx = -1e30f;
#pragma unroll
    for (int sd = 0; sd < 2; ++sd) {
      int s = sp * 2 + sd;
      float a = b2[o];
#pragma unroll
      for (int ic = 0; ic < 5; ++ic)
#pragma unroll
        for (int k = 0; k < 3; ++k) {
          int ss = s + k - 1;
          if (ss >= 0 && ss < 512) a += c1s[ic][ss] * w2[(o * 5 + ic) * 3 + k];
        }
      mx = fmaxf(mx, eluf(a));
    }
    flat[r] = mx;
  }
  __syncthreads();
  {
    float a = fb1[tid];
    for (int i2 = 0; i2 < 512; ++i2) a += flat[i2] * fw1[i2 * 256 + tid];
    z1[tid] = eluf(a);
  }
  __syncthreads();
  if (tid < 128) {
    float a = fb2[tid];
    for (int i2 = 0; i2 < 256; ++i2) a += z1[i2] * fw2[i2 * 128 + tid];
    z2[tid] = eluf(a);
  }
  __syncthreads();
  if (tid < 96) {
    float a = fb3[tid];
    for (int i2 = 0; i2 < 128; ++i2) a += z2[i2] * fw3[i2 * 96 + tid];
    z3[tid] = a;
  }
  __syncthreads();
  if (tid < 96) {
    float mu = 0.f;
    for (int j = 0; j < 96; ++j) mu += z3[j];
    mu *= (1.f / 96.f);
    float sq = 0.f;
    for (int j = 0; j < 96; ++j) {
      float d = z3[j] - mu;
      sq += d * d;
    }
    float var = sq * (1.f / 96.f);
    out[b * 96 + tid] = (z3[tid] - mu) / sqrtf(var + 1e-5f) * g[tid] + be[tid];
  }
}

// ---------------------------------------------------------------------------
extern "C" void kernel_launch(void* const* d_in, const int* in_sizes, int n_in,
                              void* d_out, int out_size, void* d_ws,
                              size_t ws_size, hipStream_t stream) {
  (void)in_sizes; (void)n_in; (void)out_size;
  const float* x    = (const float*)d_in[0];
  const float* embW = (const float*)d_in[1];
  const float* embB = (const float*)d_in[2];
  const float* Wq   = (const float*)d_in[3];
  const float* bq   = (const float*)d_in[4];
  const float* Wk   = (const float*)d_in[5];
  const float* bk   = (const float*)d_in[6];
  const float* Wv   = (const float*)d_in[7];
  const float* bv   = (const float*)d_in[8];
  const float* Wo   = (const float*)d_in[9];
  const float* bo   = (const float*)d_in[10];
  const float* c1w  = (const float*)d_in[11];
  const float* c1b  = (const float*)d_in[12];
  const float* c2w  = (const float*)d_in[13];
  const float* c2b  = (const float*)d_in[14];
  const float* f1w  = (const float*)d_in[15];
  const float* f1b  = (const float*)d_in[16];
  const float* f2w  = (const float*)d_in[17];
  const float* f2b_ = (const float*)d_in[18];
  const float* f3w  = (const float*)d_in[19];
  const float* f3b  = (const float*)d_in[20];
  const float* lng  = (const float*)d_in[21];
  const float* lnb  = (const float*)d_in[22];
  float* out = (float*)d_out;

  char* p = (char*)d_ws;
  const size_t NEED_BIG = 282779776;
  const size_t NEED_SMALL = 148561984;
  const bool big = (ws_size >= NEED_BIG);
  const long MS = 8388608;  // per-module stride in u16 elements (16 MB)

  // common prep region
  u16*   A_pe    = (u16*)(p + 0);
  u16*   WTqkv   = (u16*)(p + 524288);
  float* pb_bias = (float*)(p + 6815744);
  float* EW      = (float*)(p + 6840320);
  u16*   PB      = (u16*)(p + 6938624);

  prep_pe<<<536, 256, 0, stream>>>(embB, bq, bk, bv, A_pe, pb_bias);
  transw<<<dim3(12, 8, 8), 256, 0, stream>>>(Wq, Wk, Wv, WTqkv);
  ew_kernel<<<12, 256, 0, stream>>>(Wq, Wk, Wv, embW, EW);
  gemm_bt<true><<<dim3(4, 4, 12), 256, 0, stream>>>(
      A_pe, 0, 512, WTqkv, pb_bias, (void*)PB, 262144, 512);

  u16* ctx4;
  u16* WEFFT;
  float* bias_t;
  float* t_buf;

  if (big) {
    u16* Q4  = (u16*)(p + 13230080);
    u16* K4  = (u16*)(p + 80338944);
    u16* VT4 = (u16*)(p + 147447808);
    u16* V4  = (u16*)(p + 214556672);  // aliased: becomes ctx4 after vtrans
    ctx4   = V4;
    WEFFT  = (u16*)(p + 281665536);
    bias_t = (float*)(p + 281731072);
    t_buf  = (float*)(p + 281731200);
    weff_kernel<<<2049, 64, 0, stream>>>(Wo, bo, c1w, WEFFT, bias_t);
    qkv_all<<<16384, 256, 0, stream>>>(x, EW, PB, Q4, K4, V4, 0, 4, MS);
    vtrans<<<dim3(256, 8, 4), 256, 0, stream>>>(V4, VT4, MS);
    attn_kernel<<<dim3(256, 4, 4), 256, 0, stream>>>(Q4, K4, VT4, ctx4, MS);
  } else {
    u16* Qm  = (u16*)(p + 13230080);
    u16* Km  = (u16*)(p + 30007296);
    u16* Vm  = (u16*)(p + 46784512);
    u16* VTm = (u16*)(p + 63561728);
    ctx4   = (u16*)(p + 80338944);
    WEFFT  = (u16*)(p + 147447808);
    bias_t = (float*)(p + 147513344);
    t_buf  = (float*)(p + 147513408);
    if (ws_size < NEED_SMALL) return;
    weff_kernel<<<2049, 64, 0, stream>>>(Wo, bo, c1w, WEFFT, bias_t);
    for (int m = 0; m < 4; ++m) {
      qkv_all<<<16384, 256, 0, stream>>>(x, EW, PB, Qm, Km, Vm, m, 1, 0);
      vtrans<<<dim3(256, 8, 1), 256, 0, stream>>>(Vm, VTm, 0);
      attn_kernel<<<dim3(256, 4, 1), 256, 0, stream>>>(Qm, Km, VTm,
                                                       ctx4 + (long)m * MS, 0);
    }
  }

  t_gemm<<<1024, 64, 0, stream>>>(ctx4, WEFFT, t_buf);
  tail_kernel<<<32, 256, 0, stream>>>(t_buf, bias_t, c1b, c2w, c2b, f1w, f1b,
                                      f2w, f2b_, f3w, f3b, lng, lnb, out);
}

// Round 6
// 353.566 us; speedup vs baseline: 1.1536x; 1.1536x over previous
//
#include <hip/hip_runtime.h>
#include <math.h>

typedef unsigned short u16;
typedef unsigned int u32;
typedef __attribute__((ext_vector_type(8))) short short8;
typedef __attribute__((ext_vector_type(4))) float f32x4;
typedef __attribute__((ext_vector_type(16))) float f32x16;
typedef __attribute__((ext_vector_type(4))) u32 u32x4;
typedef __attribute__((ext_vector_type(2))) u32 u32x2;

__device__ inline u16 f2b(float f) {
  u32 u = __builtin_bit_cast(u32, f);
  u32 r = u + 0x7fffu + ((u >> 16) & 1u);
  return (u16)(r >> 16);
}
__device__ inline float b2f(u16 b) {
  return __builtin_bit_cast(float, (u32)b << 16);
}
__device__ inline u32 pk2(float a, float b) {
  return (u32)f2b(a) | ((u32)f2b(b) << 16);
}
__device__ inline float eluf(float x) { return x > 0.f ? x : expf(x) - 1.f; }

__device__ inline f32x4 mfma16(short8 a, short8 b, f32x4 c) {
  return __builtin_amdgcn_mfma_f32_16x16x32_bf16(a, b, c, 0, 0, 0);
}
__device__ inline f32x16 mfma32(short8 a, short8 b, f32x16 c) {
  return __builtin_amdgcn_mfma_f32_32x32x16_bf16(a, b, c, 0, 0, 0);
}
__device__ inline void gload16(const u16* g, u16* l) {
  __builtin_amdgcn_global_load_lds((__attribute__((address_space(1))) void*)(g),
                                   (__attribute__((address_space(3))) void*)(l),
                                   16, 0, 0);
}

// ---------------------------------------------------------------------------
// prep: A_pe[s][d] = PE[s][d] + emb_b[d]  (bf16)   and pb_bias[12][512] gather
// ---------------------------------------------------------------------------
__global__ __launch_bounds__(256) void prep_pe(
    const float* __restrict__ emb_b, const float* __restrict__ bq,
    const float* __restrict__ bk, const float* __restrict__ bv,
    u16* __restrict__ A_pe, float* __restrict__ pb_bias) {
  int bid = blockIdx.x, t = threadIdx.x;
  if (bid < 512) {
    int s = bid;
    float div = expf((2.f * t) * (-9.210340371976184f / 512.f));
    float arg = (float)s * div;
    A_pe[s * 512 + 2 * t] = f2b(sinf(arg) + emb_b[2 * t]);
    A_pe[s * 512 + 2 * t + 1] = f2b(cosf(arg) + emb_b[2 * t + 1]);
  } else {
    int i = (bid - 512) * 256 + t;  // 0..6143
    int z = i >> 9, e = i & 511;
    int ty = z >> 2, m = z & 3;
    const float* bp = (ty == 0) ? bq : (ty == 1) ? bk : bv;
    pb_bias[i] = bp[m * 512 + e];
  }
}

// ---------------------------------------------------------------------------
// transpose the 12 QKV weight matrices -> bf16 [e][d]
// ---------------------------------------------------------------------------
__global__ __launch_bounds__(256) void transw(
    const float* __restrict__ Wq, const float* __restrict__ Wk,
    const float* __restrict__ Wv, u16* __restrict__ WTqkv) {
  __shared__ float tile[64][65];
  int mid = blockIdx.x;
  const float* W = ((mid < 4) ? Wq : (mid < 8) ? Wk : Wv) + (long)(mid & 3) * 262144;
  u16* WT = WTqkv + (long)mid * 262144;
  int d0 = blockIdx.y * 64, e0 = blockIdx.z * 64;
  int t = threadIdx.x;
  int dr = t >> 2, ec = (t & 3) * 16;
#pragma unroll
  for (int j = 0; j < 16; j += 4) {
    float4 v = *(const float4*)&W[(long)(d0 + dr) * 512 + e0 + ec + j];
    tile[dr][ec + j] = v.x;
    tile[dr][ec + j + 1] = v.y;
    tile[dr][ec + j + 2] = v.z;
    tile[dr][ec + j + 3] = v.w;
  }
  __syncthreads();
  int er = t >> 2, dc = (t & 3) * 16;
  u16 tmp[16] __attribute__((aligned(16)));
#pragma unroll
  for (int j = 0; j < 16; ++j) tmp[j] = f2b(tile[dc + j][er]);
  *(short8*)&WT[(long)(e0 + er) * 512 + d0 + dc] = *(short8*)&tmp[0];
  *(short8*)&WT[(long)(e0 + er) * 512 + d0 + dc + 8] = *(short8*)&tmp[8];
}

// ---------------------------------------------------------------------------
// EW[z][f][e] = sum_d emb_W[f][d] * W_z[d][e]  — single pass over W per z
// ---------------------------------------------------------------------------
__global__ __launch_bounds__(256) void ew_kernel(
    const float* __restrict__ Wq, const float* __restrict__ Wk,
    const float* __restrict__ Wv, const float* __restrict__ embW,
    float* __restrict__ EW) {
  __shared__ float eb[4][512];
  int z = blockIdx.x;
  const float* W = ((z < 4) ? Wq : (z < 8) ? Wk : Wv) + (long)(z & 3) * 262144;
  int t = threadIdx.x;
#pragma unroll
  for (int i = 0; i < 8; ++i) eb[0][t + i * 256] = embW[t + i * 256];
  __syncthreads();
  float a[4][2] = {};
  for (int d = 0; d < 512; ++d) {
    float w0 = W[(long)d * 512 + t];
    float w1v = W[(long)d * 512 + t + 256];
#pragma unroll
    for (int f = 0; f < 4; ++f) {
      float e = eb[f][d];
      a[f][0] += e * w0;
      a[f][1] += e * w1v;
    }
  }
#pragma unroll
  for (int f = 0; f < 4; ++f) {
    EW[((long)z * 4 + f) * 512 + t] = a[f][0];
    EW[((long)z * 4 + f) * 512 + t + 256] = a[f][1];
  }
}

// ---------------------------------------------------------------------------
// WEFF_m[d][j] = sum_e Wo_m[d][e] * w1[o][m*512+e][k]  (j = o*3+k, 15 + pad)
// ---------------------------------------------------------------------------
__global__ __launch_bounds__(64) void weff_kernel(
    const float* __restrict__ Wo, const float* __restrict__ bo,
    const float* __restrict__ w1, u16* __restrict__ WEFFT,
    float* __restrict__ bias_t) {
  const int bid = blockIdx.x, l = threadIdx.x;
  if (bid < 2048) {
    int m = bid >> 9, d = bid & 511;
    const float* wrow = Wo + ((long)m * 512 + d) * 512;
    float a[15] = {};
#pragma unroll
    for (int i = 0; i < 8; ++i) {
      int e = l * 8 + i;
      float wv = wrow[e];
#pragma unroll
      for (int o = 0; o < 5; ++o)
#pragma unroll
        for (int k = 0; k < 3; ++k)
          a[o * 3 + k] += wv * w1[((long)o * 2048 + m * 512 + e) * 3 + k];
    }
#pragma unroll
    for (int j = 0; j < 15; ++j) {
      float v = a[j];
      for (int o = 1; o < 64; o <<= 1) v += __shfl_xor(v, o);
      if (l == 0) WEFFT[((long)m * 16 + j) * 512 + d] = f2b(v);
    }
    if (l == 0) WEFFT[((long)m * 16 + 15) * 512 + d] = 0;
  } else {
    float a[15] = {};
    for (int c = l; c < 2048; c += 64) {
      float bv = bo[c];
#pragma unroll
      for (int o = 0; o < 5; ++o)
#pragma unroll
        for (int k = 0; k < 3; ++k)
          a[o * 3 + k] += bv * w1[((long)o * 2048 + c) * 3 + k];
    }
#pragma unroll
    for (int j = 0; j < 15; ++j) {
      float v = a[j];
      for (int o = 1; o < 64; o <<= 1) v += __shfl_xor(v, o);
      if (l == 0) bias_t[j] = v;
    }
    if (l == 0) bias_t[15] = 0.f;
  }
}

// ---------------------------------------------------------------------------
// generic bf16 GEMM  C[r][c] = sum_k A[r][k] * BT[c][k] + bias[c]
// ---------------------------------------------------------------------------
template <bool OBF>
__global__ __launch_bounds__(256) void gemm_bt(
    const u16* __restrict__ A, long sAz, int lda, const u16* __restrict__ BT,
    const float* __restrict__ bias, void* __restrict__ out, long sOz, int ldo) {
  __shared__ u16 As[128 * 32];
  __shared__ u16 Bs[128 * 32];
  const int z = blockIdx.z;
  const int tid = threadIdx.x, w = tid >> 6, l = tid & 63;
  const long row0 = (long)blockIdx.y * 128;
  const u16* Ab = A + (long)z * sAz + row0 * lda;
  const u16* Bb = BT + (long)z * 262144 + (long)blockIdx.x * 128 * 512;
  const u16* ga = Ab + (long)(w * 32 + (l >> 2)) * lda + (l & 3) * 8;
  const u16* gb = Bb + (long)(w * 32 + (l >> 2)) * 512 + (l & 3) * 8;
  u16* lA = As + w * 32 * 32;
  u16* lB = Bs + w * 32 * 32;
  f32x4 acc[4][4] = {};
  const int wr = (w >> 1) * 64, wc = (w & 1) * 64;
  for (int kt = 0; kt < 16; ++kt) {
    gload16(ga + kt * 32, lA);
    gload16(ga + kt * 32 + 16 * lda, lA + 16 * 32);
    gload16(gb + kt * 32, lB);
    gload16(gb + kt * 32 + 16 * 512, lB + 16 * 32);
    __syncthreads();
    short8 af[4], bf[4];
#pragma unroll
    for (int i = 0; i < 4; ++i)
      af[i] = *(const short8*)&As[(wr + i * 16 + (l & 15)) * 32 + (l >> 4) * 8];
#pragma unroll
    for (int i = 0; i < 4; ++i)
      bf[i] = *(const short8*)&Bs[(wc + i * 16 + (l & 15)) * 32 + (l >> 4) * 8];
#pragma unroll
    for (int i = 0; i < 4; ++i)
#pragma unroll
      for (int j = 0; j < 4; ++j) acc[i][j] = mfma16(af[i], bf[j], acc[i][j]);
    __syncthreads();
  }
  const int colB = blockIdx.x * 128 + wc;
#pragma unroll
  for (int i = 0; i < 4; ++i)
#pragma unroll
    for (int j = 0; j < 4; ++j) {
      int col = colB + j * 16 + (l & 15);
      float bb = bias[(long)z * 512 + col];
#pragma unroll
      for (int q = 0; q < 4; ++q) {
        long r = row0 + wr + i * 16 + (l >> 4) * 4 + q;
        float v = acc[i][j][q] + bb;
        if (OBF)
          ((u16*)out)[(long)z * sOz + r * ldo + col] = f2b(v);
        else
          ((float*)out)[(long)z * sOz + r * ldo + col] = v;
      }
    }
}

// ---------------------------------------------------------------------------
// QKV generation: rank-4 update + PB table (bf16), fused per-head L2 norm.
// ---------------------------------------------------------------------------
__global__ __launch_bounds__(256) void qkv_all(
    const float* __restrict__ x, const float* __restrict__ EW,
    const u16* __restrict__ PB, u16* __restrict__ Q, u16* __restrict__ K,
    u16* __restrict__ V, int m0, int nm, long mstride) {
  const int rid = blockIdx.x;  // b*512+s
  const int s = rid & 511;
  const int t = threadIdx.x;
  const float* xr = x + (long)rid * 7;
  const float x0 = xr[0], x1 = xr[1], x2 = xr[2];
  for (int mm = 0; mm < nm; ++mm) {
    const int m = m0 + mm;
    const float xd = xr[3 + m];
    const long obase = (long)mm * mstride + (long)rid * 512 + 2 * t;
    float2 res[3];
#pragma unroll
    for (int ty = 0; ty < 3; ++ty) {
      int z = ty * 4 + m;
      const float* ew = EW + (long)z * 4 * 512;
      float2 e0 = *(const float2*)&ew[0 * 512 + 2 * t];
      float2 e1 = *(const float2*)&ew[1 * 512 + 2 * t];
      float2 e2 = *(const float2*)&ew[2 * 512 + 2 * t];
      float2 e3 = *(const float2*)&ew[3 * 512 + 2 * t];
      u32 pb2 = *(const u32*)&PB[((long)z * 512 + s) * 512 + 2 * t];
      res[ty].x = xd * e0.x + x0 * e1.x + x1 * e2.x + x2 * e3.x + b2f((u16)pb2);
      res[ty].y =
          xd * e0.y + x0 * e1.y + x1 * e2.y + x2 * e3.y + b2f((u16)(pb2 >> 16));
    }
    *(u32*)&V[obase] = pk2(res[2].x, res[2].y);
#pragma unroll
    for (int ty = 0; ty < 2; ++ty) {
      float ss = res[ty].x * res[ty].x + res[ty].y * res[ty].y;
      for (int o = 1; o < 32; o <<= 1) ss += __shfl_xor(ss, o);
      float sc = 1.f / fmaxf(sqrtf(ss), 1e-12f);
      u16* P = ty ? K : Q;
      *(u32*)&P[obase] = pk2(res[ty].x * sc, res[ty].y * sc);
    }
  }
}

// ---------------------------------------------------------------------------
// V transpose: VT[(b*8+h)*64 + dk][s] = V[(b*512+s)][h*64+dk]; z = module
// ---------------------------------------------------------------------------
__global__ __launch_bounds__(256) void vtrans(const u16* __restrict__ Vg,
                                              u16* __restrict__ VTg,
                                              long mstride) {
  __shared__ u16 tile[64][72];
  const u16* V = Vg + (long)blockIdx.z * mstride;
  u16* VT = VTg + (long)blockIdx.z * mstride;
  int bh = blockIdx.x;
  int b = bh >> 3, h = bh & 7;
  int st = blockIdx.y;
  int t = threadIdx.x;
  int sr = t >> 2, kc = (t & 3) * 16;
  long gsrc = ((long)b * 512 + st * 64 + sr) * 512 + h * 64 + kc;
  *(short8*)&tile[sr][kc] = *(const short8*)&V[gsrc];
  *(short8*)&tile[sr][kc + 8] = *(const short8*)&V[gsrc + 8];
  __syncthreads();
  int kr = t >> 2, sc = (t & 3) * 16;
  u16 tmp[16] __attribute__((aligned(16)));
#pragma unroll
  for (int j = 0; j < 16; ++j) tmp[j] = tile[sc + j][kr];
  long gdst = ((long)bh * 64 + kr) * 512 + st * 64 + sc;
  *(short8*)&VT[gdst] = *(short8*)&tmp[0];
  *(short8*)&VT[gdst + 8] = *(short8*)&tmp[8];
}

// ---------------------------------------------------------------------------
// flash attention, max-free, 32x32 swapped-operand form.
// S^T = mfma32(K_frag, Q_frag): lane owns q = l&31; k rows in C regs.
// P^T built in-register via pk2 + shfl_xor(32) (T12 pattern) -> PV B-operand.
// O^T = mfma32(VT_frag, PT_frag). No P LDS buffer. l via per-lane f32 sum.
// ---------------------------------------------------------------------------
__global__ __launch_bounds__(256, 4) void attn_kernel(
    const u16* __restrict__ Qg, const u16* __restrict__ Kg,
    const u16* __restrict__ VTg, u16* __restrict__ ctxg, long mstride) {
  __shared__ u16 Kb[2][64][64];
  __shared__ u16 Vb[2][64][64];
  const u16* Q = Qg + (long)blockIdx.z * mstride;
  const u16* K = Kg + (long)blockIdx.z * mstride;
  const u16* VT = VTg + (long)blockIdx.z * mstride;
  u16* ctx = ctxg + (long)blockIdx.z * mstride;
  const int bh = blockIdx.x;  // b*8+h
  const int qb = blockIdx.y;
  const int b = bh >> 3, h = bh & 7;
  const int tid = threadIdx.x, w = tid >> 6, l = tid & 63;
  const int lq = l & 31, hi = l >> 5, l7 = l & 7;
  const long rowbase = (long)b * 512;
  const int hoff = h * 64;
  const int rw = l >> 3, gch = (l & 7) ^ rw;

  // Q fragments (B-operand: col = q = lq, k-elem = d = dc*16 + hi*8 + j)
  short8 qf[4];
  {
    const u16* qrow =
        Q + (rowbase + qb * 128 + w * 32 + lq) * 512 + hoff + hi * 8;
#pragma unroll
    for (int dc = 0; dc < 4; ++dc) qf[dc] = *(const short8*)(qrow + dc * 16);
  }

  f32x16 o_acc[2] = {};
  float l_run = 0.f;

  const u16* Kgbase = K + rowbase * 512 + hoff + gch * 8;
  const u16* Vgbase = VT + (long)bh * 64 * 512 + gch * 8;

#define STAGE(bf, kt)                                                         \
  {                                                                           \
    _Pragma("unroll") for (int i = 0; i < 2; ++i) {                           \
      int rr = w * 16 + i * 8;                                                \
      gload16(Kgbase + (long)((kt)*64 + rr + rw) * 512, &Kb[bf][rr][0]);      \
      gload16(Vgbase + (long)(rr + rw) * 512 + (kt)*64, &Vb[bf][rr][0]);      \
    }                                                                         \
  }

  STAGE(0, 0);
  __syncthreads();

  for (int kt = 0; kt < 8; ++kt) {
    const int cur = kt & 1;
    if (kt < 7) STAGE(cur ^ 1, kt + 1);  // async prefetch in flight
    float tsum = 0.f;
    __builtin_amdgcn_s_setprio(1);
#pragma unroll
    for (int ktile = 0; ktile < 2; ++ktile) {
      // S^T (32k x 32q), contraction over d = 64 (4 chunks of 16)
      f32x16 s = {};
#pragma unroll
      for (int dc = 0; dc < 4; ++dc) {
        short8 kf = *(const short8*)((const char*)&Kb[cur][ktile * 32 + lq][0] +
                                     (((dc * 2 + hi) ^ l7) * 16));
        s = mfma32(kf, qf[dc], s);
      }
      // P = exp(S)  (|S| <= ~1, bounded)
      float p[16];
#pragma unroll
      for (int r = 0; r < 16; ++r) {
        p[r] = __expf(s[r]);
        tsum += p[r];
      }
      // pack C-reg pairs: A_i k-coverage per m74/m101 layout
      u32 A0 = pk2(p[0], p[1]), A1 = pk2(p[2], p[3]);
      u32 A2 = pk2(p[4], p[5]), A3 = pk2(p[6], p[7]);
      u32 A4 = pk2(p[8], p[9]), A5 = pk2(p[10], p[11]);
      u32 A6 = pk2(p[12], p[13]), A7 = pk2(p[14], p[15]);
      u32 pA0 = __shfl_xor(A0, 32), pA1 = __shfl_xor(A1, 32);
      u32 pA2 = __shfl_xor(A2, 32), pA3 = __shfl_xor(A3, 32);
      u32 pA4 = __shfl_xor(A4, 32), pA5 = __shfl_xor(A5, 32);
      u32 pA6 = __shfl_xor(A6, 32), pA7 = __shfl_xor(A7, 32);
      // B-operand frags: lane needs k = kc*16 + hi*8 + j
      u32x4 f0 = {hi ? pA2 : A0, hi ? pA3 : A1, hi ? A2 : pA0, hi ? A3 : pA1};
      u32x4 f1 = {hi ? pA6 : A4, hi ? pA7 : A5, hi ? A6 : pA4, hi ? A7 : pA5};
      short8 bf0 = __builtin_bit_cast(short8, f0);
      short8 bf1 = __builtin_bit_cast(short8, f1);
      // PV: O^T += V^T-frag x P^T-frag, for the 2 k-chunks of this ktile
#pragma unroll
      for (int kk2 = 0; kk2 < 2; ++kk2) {
        const int kc = ktile * 2 + kk2;
        short8 pb = kk2 ? bf1 : bf0;
#pragma unroll
        for (int dt = 0; dt < 2; ++dt) {
          short8 vf =
              *(const short8*)((const char*)&Vb[cur][dt * 32 + lq][0] +
                               (((kc * 2 + hi) ^ l7) * 16));
          o_acc[dt] = mfma32(vf, pb, o_acc[dt]);
        }
      }
    }
    __builtin_amdgcn_s_setprio(0);
    l_run += tsum + __shfl_xor(tsum, 32);
    __syncthreads();  // drains prefetch vmcnt + frees cur buffer
  }
#undef STAGE
  const float inv = 1.f / l_run;
  u16* crow = ctx + (rowbase + qb * 128 + w * 32 + lq) * 512 + hoff + hi * 4;
#pragma unroll
  for (int dt = 0; dt < 2; ++dt)
#pragma unroll
    for (int rq = 0; rq < 4; ++rq) {
      u32 w0 = pk2(o_acc[dt][rq * 4 + 0] * inv, o_acc[dt][rq * 4 + 1] * inv);
      u32 w1 = pk2(o_acc[dt][rq * 4 + 2] * inv, o_acc[dt][rq * 4 + 3] * inv);
      u32x2 pr = {w0, w1};
      *(u32x2*)&crow[dt * 32 + rq * 8] = pr;
    }
}

// ---------------------------------------------------------------------------
// t[r][j] = sum_m ctx_m[r][:] . WEFFT[m][j][:]
// ---------------------------------------------------------------------------
__global__ __launch_bounds__(64) void t_gemm(const u16* __restrict__ ctx4,
                                             const u16* __restrict__ WEFFT,
                                             float* __restrict__ t) {
  const int l = threadIdx.x;
  const long r0 = (long)blockIdx.x * 16;
  f32x4 acc = {};
#pragma unroll
  for (int m = 0; m < 4; ++m) {
    const u16* A =
        ctx4 + (long)m * 8388608 + (r0 + (l & 15)) * 512 + (l >> 4) * 8;
    const u16* Bb = WEFFT + m * 8192 + (l & 15) * 512 + (l >> 4) * 8;
#pragma unroll
    for (int kt = 0; kt < 16; ++kt) {
      short8 af = *(const short8*)(A + kt * 32);
      short8 bf = *(const short8*)(Bb + kt * 32);
      acc = mfma16(af, bf, acc);
    }
  }
#pragma unroll
  for (int q = 0; q < 4; ++q)
    t[(r0 + (l >> 4) * 4 + q) * 16 + (l & 15)] = acc[q];
}

// ---------------------------------------------------------------------------
// tail1: c1 (from t) + elu -> conv2 + elu + pool -> flat (global, f32)
// ---------------------------------------------------------------------------
__global__ __launch_bounds__(256) void tail1_kernel(
    const float* __restrict__ t, const float* __restrict__ bias_t,
    const float* __restrict__ b1, const float* __restrict__ w2,
    const float* __restrict__ b2, float* __restrict__ flat) {
  __shared__ float ts[512][16];
  __shared__ float c1s[5][512];
  int b = blockIdx.x, tid = threadIdx.x;
  const float4* tsrc = (const float4*)(t + (long)b * 8192);
  float4* tdst = (float4*)&ts[0][0];
#pragma unroll
  for (int i = 0; i < 8; ++i) tdst[tid + i * 256] = tsrc[tid + i * 256];
  __syncthreads();
#pragma unroll
  for (int i = 0; i < 10; ++i) {
    int idx = tid + i * 256;  // 0..2559
    int o = idx >> 9, s = idx & 511;
    float a = b1[o];
#pragma unroll
    for (int k = 0; k < 3; ++k) {
      int ss = s + k - 1;
      if (ss >= 0 && ss < 512) a += ts[ss][o * 3 + k] + bias_t[o * 3 + k];
    }
    c1s[o][s] = eluf(a);
  }
  __syncthreads();
#pragma unroll
  for (int i = 0; i < 2; ++i) {
    int r = tid + i * 256;  // 0..511
    int o = r >> 8, sp = r & 255;
    float mx = -1e30f;
#pragma unroll
    for (int sd = 0; sd < 2; ++sd) {
      int s = sp * 2 + sd;
      float a = b2[o];
#pragma unroll
      for (int ic = 0; ic < 5; ++ic)
#pragma unroll
        for (int k = 0; k < 3; ++k) {
          int ss = s + k - 1;
          if (ss >= 0 && ss < 512) a += c1s[ic][ss] * w2[(o * 5 + ic) * 3 + k];
        }
      mx = fmaxf(mx, eluf(a));
    }
    flat[(long)b * 512 + r] = mx;
  }
}

// ---------------------------------------------------------------------------
// head: fc1+fc2+fc3+LN; 1024 threads, split-K partials for latency hiding
// ---------------------------------------------------------------------------
__global__ __launch_bounds__(1024) void head_kernel(
    const float* __restrict__ flat, const float* __restrict__ fw1,
    const float* __restrict__ fb1, const float* __restrict__ fw2,
    const float* __restrict__ fb2, const float* __restrict__ fw3,
    const float* __restrict__ fb3, const float* __restrict__ g,
    const float* __restrict__ be, float* __restrict__ out) {
  __shared__ float xb[512];
  __shared__ float z1p[4][256];
  __shared__ float z1[256];
  __shared__ float z2p[2][128];
  __shared__ float z2[128];
  __shared__ float z3[96];
  int b = blockIdx.x, t = threadIdx.x;
  if (t < 512) xb[t] = flat[(long)b * 512 + t];
  __syncthreads();
  {
    int o = t & 255, part = t >> 8;
    float a = 0.f;
    const float* wp = fw1 + (long)part * 128 * 256 + o;
    const float* xp = xb + part * 128;
#pragma unroll 8
    for (int i = 0; i < 128; ++i) a += xp[i] * wp[i * 256];
    z1p[part][o] = a;
  }
  __syncthreads();
  if (t < 256)
    z1[t] = eluf(fb1[t] + z1p[0][t] + z1p[1][t] + z1p[2][t] + z1p[3][t]);
  __syncthreads();
  if (t < 256) {
    int o = t & 127, part = t >> 7;
    float a = 0.f;
    const float* wp = fw2 + (long)part * 128 * 128 + o;
    const float* xp = z1 + part * 128;
#pragma unroll 8
    for (int i = 0; i < 128; ++i) a += xp[i] * wp[i * 128];
    z2p[part][o] = a;
  }
  __syncthreads();
  if (t < 128) z2[t] = eluf(fb2[t] + z2p[0][t] + z2p[1][t]);
  __syncthreads();
  if (t < 96) {
    float a = fb3[t];
#pragma unroll 8
    for (int i = 0; i < 128; ++i) a += z2[i] * fw3[i * 96 + t];
    z3[t] = a;
  }
  __syncthreads();
  if (t < 96) {
    float mu = 0.f;
    for (int j = 0; j < 96; ++j) mu += z3[j];
    mu *= (1.f / 96.f);
    float sq = 0.f;
    for (int j = 0; j < 96; ++j) {
      float d = z3[j] - mu;
      sq += d * d;
    }
    float var = sq * (1.f / 96.f);
    out[b * 96 + t] = (z3[t] - mu) / sqrtf(var + 1e-5f) * g[t] + be[t];
  }
}

// ---------------------------------------------------------------------------
extern "C" void kernel_launch(void* const* d_in, const int* in_sizes, int n_in,
                              void* d_out, int out_size, void* d_ws,
                              size_t ws_size, hipStream_t stream) {
  (void)in_sizes; (void)n_in; (void)out_size;
  const float* x    = (const float*)d_in[0];
  const float* embW = (const float*)d_in[1];
  const float* embB = (const float*)d_in[2];
  const float* Wq   = (const float*)d_in[3];
  const float* bq   = (const float*)d_in[4];
  const float* Wk   = (const float*)d_in[5];
  const float* bk   = (const float*)d_in[6];
  const float* Wv   = (const float*)d_in[7];
  const float* bv   = (const float*)d_in[8];
  const float* Wo   = (const float*)d_in[9];
  const float* bo   = (const float*)d_in[10];
  const float* c1w  = (const float*)d_in[11];
  const float* c1b  = (const float*)d_in[12];
  const float* c2w  = (const float*)d_in[13];
  const float* c2b  = (const float*)d_in[14];
  const float* f1w  = (const float*)d_in[15];
  const float* f1b  = (const float*)d_in[16];
  const float* f2w  = (const float*)d_in[17];
  const float* f2b_ = (const float*)d_in[18];
  const float* f3w  = (const float*)d_in[19];
  const float* f3b  = (const float*)d_in[20];
  const float* lng  = (const float*)d_in[21];
  const float* lnb  = (const float*)d_in[22];
  float* out = (float*)d_out;

  char* p = (char*)d_ws;
  const size_t NEED = 215736448;
  if (ws_size < NEED) return;
  const long MS = 8388608;  // per-module stride in u16 elements (16 MB)

  u16*   A_pe    = (u16*)(p + 0);
  u16*   WTqkv   = (u16*)(p + 524288);
  float* pb_bias = (float*)(p + 6815744);
  float* EW      = (float*)(p + 6840320);
  u16*   PB      = (u16*)(p + 6938624);
  u16*   Q2      = (u16*)(p + 13230080);
  u16*   K2      = (u16*)(p + 46784512);
  u16*   V2      = (u16*)(p + 80338944);
  u16*   VT2     = (u16*)(p + 113893376);
  u16*   ctx4    = (u16*)(p + 147447808);
  u16*   WEFFT   = (u16*)(p + 214556672);
  float* bias_t  = (float*)(p + 214622208);
  float* t_buf   = (float*)(p + 214622336);
  float* flat    = (float*)(p + 215670912);

  prep_pe<<<536, 256, 0, stream>>>(embB, bq, bk, bv, A_pe, pb_bias);
  transw<<<dim3(12, 8, 8), 256, 0, stream>>>(Wq, Wk, Wv, WTqkv);
  ew_kernel<<<12, 256, 0, stream>>>(Wq, Wk, Wv, embW, EW);
  weff_kernel<<<2049, 64, 0, stream>>>(Wo, bo, c1w, WEFFT, bias_t);
  gemm_bt<true><<<dim3(4, 4, 12), 256, 0, stream>>>(
      A_pe, 0, 512, WTqkv, pb_bias, (void*)PB, 262144, 512);

  for (int gp = 0; gp < 2; ++gp) {
    qkv_all<<<16384, 256, 0, stream>>>(x, EW, PB, Q2, K2, V2, gp * 2, 2, MS);
    vtrans<<<dim3(256, 8, 2), 256, 0, stream>>>(V2, VT2, MS);
    attn_kernel<<<dim3(256, 4, 2), 256, 0, stream>>>(
        Q2, K2, VT2, ctx4 + (long)gp * 2 * MS, MS);
  }

  t_gemm<<<1024, 64, 0, stream>>>(ctx4, WEFFT, t_buf);
  tail1_kernel<<<32, 256, 0, stream>>>(t_buf, bias_t, c1b, c2w, c2b, flat);
  head_kernel<<<32, 1024, 0, stream>>>(flat, f1w, f1b, f2w, f2b_, f3w, f3b,
                                       lng, lnb, out);
}

// Round 7
// 281.340 us; speedup vs baseline: 1.4498x; 1.2567x over previous
//
#include <hip/hip_runtime.h>
#include <math.h>

typedef unsigned short u16;
typedef unsigned int u32;
typedef __attribute__((ext_vector_type(8))) short short8;
typedef __attribute__((ext_vector_type(4))) float f32x4;
typedef __attribute__((ext_vector_type(16))) float f32x16;
typedef __attribute__((ext_vector_type(4))) u32 u32x4;
typedef __attribute__((ext_vector_type(2))) u32 u32x2;

__device__ inline u16 f2b(float f) {
  u32 u = __builtin_bit_cast(u32, f);
  u32 r = u + 0x7fffu + ((u >> 16) & 1u);
  return (u16)(r >> 16);
}
__device__ inline float b2f(u16 b) {
  return __builtin_bit_cast(float, (u32)b << 16);
}
// HW packed f32->bf16 (RTNE), 1 instruction for 2 values
__device__ inline u32 cvtpk(float lo, float hi) {
  u32 r;
  asm("v_cvt_pk_bf16_f32 %0, %1, %2" : "=v"(r) : "v"(lo), "v"(hi));
  return r;
}
__device__ inline float eluf(float x) { return x > 0.f ? x : expf(x) - 1.f; }

__device__ inline f32x4 mfma16(short8 a, short8 b, f32x4 c) {
  return __builtin_amdgcn_mfma_f32_16x16x32_bf16(a, b, c, 0, 0, 0);
}
__device__ inline f32x16 mfma32(short8 a, short8 b, f32x16 c) {
  return __builtin_amdgcn_mfma_f32_32x32x16_bf16(a, b, c, 0, 0, 0);
}
__device__ inline void gload16(const u16* g, u16* l) {
  __builtin_amdgcn_global_load_lds((__attribute__((address_space(1))) void*)(g),
                                   (__attribute__((address_space(3))) void*)(l),
                                   16, 0, 0);
}

// ---------------------------------------------------------------------------
// prep: A_pe[s][d] = PE[s][d] + emb_b[d]  (bf16)   and pb_bias[12][512] gather
// ---------------------------------------------------------------------------
__global__ __launch_bounds__(256) void prep_pe(
    const float* __restrict__ emb_b, const float* __restrict__ bq,
    const float* __restrict__ bk, const float* __restrict__ bv,
    u16* __restrict__ A_pe, float* __restrict__ pb_bias) {
  int bid = blockIdx.x, t = threadIdx.x;
  if (bid < 512) {
    int s = bid;
    float div = expf((2.f * t) * (-9.210340371976184f / 512.f));
    float arg = (float)s * div;
    A_pe[s * 512 + 2 * t] = f2b(sinf(arg) + emb_b[2 * t]);
    A_pe[s * 512 + 2 * t + 1] = f2b(cosf(arg) + emb_b[2 * t + 1]);
  } else {
    int i = (bid - 512) * 256 + t;  // 0..6143
    int z = i >> 9, e = i & 511;
    int ty = z >> 2, m = z & 3;
    const float* bp = (ty == 0) ? bq : (ty == 1) ? bk : bv;
    pb_bias[i] = bp[m * 512 + e];
  }
}

// ---------------------------------------------------------------------------
// transpose the 12 QKV weight matrices -> bf16 [e][d]
// ---------------------------------------------------------------------------
__global__ __launch_bounds__(256) void transw(
    const float* __restrict__ Wq, const float* __restrict__ Wk,
    const float* __restrict__ Wv, u16* __restrict__ WTqkv) {
  __shared__ float tile[64][65];
  int mid = blockIdx.x;
  const float* W = ((mid < 4) ? Wq : (mid < 8) ? Wk : Wv) + (long)(mid & 3) * 262144;
  u16* WT = WTqkv + (long)mid * 262144;
  int d0 = blockIdx.y * 64, e0 = blockIdx.z * 64;
  int t = threadIdx.x;
  int dr = t >> 2, ec = (t & 3) * 16;
#pragma unroll
  for (int j = 0; j < 16; j += 4) {
    float4 v = *(const float4*)&W[(long)(d0 + dr) * 512 + e0 + ec + j];
    tile[dr][ec + j] = v.x;
    tile[dr][ec + j + 1] = v.y;
    tile[dr][ec + j + 2] = v.z;
    tile[dr][ec + j + 3] = v.w;
  }
  __syncthreads();
  int er = t >> 2, dc = (t & 3) * 16;
  u16 tmp[16] __attribute__((aligned(16)));
#pragma unroll
  for (int j = 0; j < 16; ++j) tmp[j] = f2b(tile[dc + j][er]);
  *(short8*)&WT[(long)(e0 + er) * 512 + d0 + dc] = *(short8*)&tmp[0];
  *(short8*)&WT[(long)(e0 + er) * 512 + d0 + dc + 8] = *(short8*)&tmp[8];
}

// ---------------------------------------------------------------------------
// EW[z][f][e] = sum_d emb_W[f][d] * W_z[d][e]  — single pass over W per z
// ---------------------------------------------------------------------------
__global__ __launch_bounds__(256) void ew_kernel(
    const float* __restrict__ Wq, const float* __restrict__ Wk,
    const float* __restrict__ Wv, const float* __restrict__ embW,
    float* __restrict__ EW) {
  __shared__ float eb[4][512];
  int z = blockIdx.x;
  const float* W = ((z < 4) ? Wq : (z < 8) ? Wk : Wv) + (long)(z & 3) * 262144;
  int t = threadIdx.x;
#pragma unroll
  for (int i = 0; i < 8; ++i) eb[0][t + i * 256] = embW[t + i * 256];
  __syncthreads();
  float a[4][2] = {};
  for (int d = 0; d < 512; ++d) {
    float w0 = W[(long)d * 512 + t];
    float w1v = W[(long)d * 512 + t + 256];
#pragma unroll
    for (int f = 0; f < 4; ++f) {
      float e = eb[f][d];
      a[f][0] += e * w0;
      a[f][1] += e * w1v;
    }
  }
#pragma unroll
  for (int f = 0; f < 4; ++f) {
    EW[((long)z * 4 + f) * 512 + t] = a[f][0];
    EW[((long)z * 4 + f) * 512 + t + 256] = a[f][1];
  }
}

// ---------------------------------------------------------------------------
// WEFF_m[d][j] = sum_e Wo_m[d][e] * w1[o][m*512+e][k]  (j = o*3+k, 15 + pad)
// ---------------------------------------------------------------------------
__global__ __launch_bounds__(64) void weff_kernel(
    const float* __restrict__ Wo, const float* __restrict__ bo,
    const float* __restrict__ w1, u16* __restrict__ WEFFT,
    float* __restrict__ bias_t) {
  const int bid = blockIdx.x, l = threadIdx.x;
  if (bid < 2048) {
    int m = bid >> 9, d = bid & 511;
    const float* wrow = Wo + ((long)m * 512 + d) * 512;
    float a[15] = {};
#pragma unroll
    for (int i = 0; i < 8; ++i) {
      int e = l * 8 + i;
      float wv = wrow[e];
#pragma unroll
      for (int o = 0; o < 5; ++o)
#pragma unroll
        for (int k = 0; k < 3; ++k)
          a[o * 3 + k] += wv * w1[((long)o * 2048 + m * 512 + e) * 3 + k];
    }
#pragma unroll
    for (int j = 0; j < 15; ++j) {
      float v = a[j];
      for (int o = 1; o < 64; o <<= 1) v += __shfl_xor(v, o);
      if (l == 0) WEFFT[((long)m * 16 + j) * 512 + d] = f2b(v);
    }
    if (l == 0) WEFFT[((long)m * 16 + 15) * 512 + d] = 0;
  } else {
    float a[15] = {};
    for (int c = l; c < 2048; c += 64) {
      float bv = bo[c];
#pragma unroll
      for (int o = 0; o < 5; ++o)
#pragma unroll
        for (int k = 0; k < 3; ++k)
          a[o * 3 + k] += bv * w1[((long)o * 2048 + c) * 3 + k];
    }
#pragma unroll
    for (int j = 0; j < 15; ++j) {
      float v = a[j];
      for (int o = 1; o < 64; o <<= 1) v += __shfl_xor(v, o);
      if (l == 0) bias_t[j] = v;
    }
    if (l == 0) bias_t[15] = 0.f;
  }
}

// ---------------------------------------------------------------------------
// generic bf16 GEMM  C[r][c] = sum_k A[r][k] * BT[c][k] + bias[c]
// ---------------------------------------------------------------------------
template <bool OBF>
__global__ __launch_bounds__(256) void gemm_bt(
    const u16* __restrict__ A, long sAz, int lda, const u16* __restrict__ BT,
    const float* __restrict__ bias, void* __restrict__ out, long sOz, int ldo) {
  __shared__ u16 As[128 * 32];
  __shared__ u16 Bs[128 * 32];
  const int z = blockIdx.z;
  const int tid = threadIdx.x, w = tid >> 6, l = tid & 63;
  const long row0 = (long)blockIdx.y * 128;
  const u16* Ab = A + (long)z * sAz + row0 * lda;
  const u16* Bb = BT + (long)z * 262144 + (long)blockIdx.x * 128 * 512;
  const u16* ga = Ab + (long)(w * 32 + (l >> 2)) * lda + (l & 3) * 8;
  const u16* gb = Bb + (long)(w * 32 + (l >> 2)) * 512 + (l & 3) * 8;
  u16* lA = As + w * 32 * 32;
  u16* lB = Bs + w * 32 * 32;
  f32x4 acc[4][4] = {};
  const int wr = (w >> 1) * 64, wc = (w & 1) * 64;
  for (int kt = 0; kt < 16; ++kt) {
    gload16(ga + kt * 32, lA);
    gload16(ga + kt * 32 + 16 * lda, lA + 16 * 32);
    gload16(gb + kt * 32, lB);
    gload16(gb + kt * 32 + 16 * 512, lB + 16 * 32);
    __syncthreads();
    short8 af[4], bf[4];
#pragma unroll
    for (int i = 0; i < 4; ++i)
      af[i] = *(const short8*)&As[(wr + i * 16 + (l & 15)) * 32 + (l >> 4) * 8];
#pragma unroll
    for (int i = 0; i < 4; ++i)
      bf[i] = *(const short8*)&Bs[(wc + i * 16 + (l & 15)) * 32 + (l >> 4) * 8];
#pragma unroll
    for (int i = 0; i < 4; ++i)
#pragma unroll
      for (int j = 0; j < 4; ++j) acc[i][j] = mfma16(af[i], bf[j], acc[i][j]);
    __syncthreads();
  }
  const int colB = blockIdx.x * 128 + wc;
#pragma unroll
  for (int i = 0; i < 4; ++i)
#pragma unroll
    for (int j = 0; j < 4; ++j) {
      int col = colB + j * 16 + (l & 15);
      float bb = bias[(long)z * 512 + col];
#pragma unroll
      for (int q = 0; q < 4; ++q) {
        long r = row0 + wr + i * 16 + (l >> 4) * 4 + q;
        float v = acc[i][j][q] + bb;
        if (OBF)
          ((u16*)out)[(long)z * sOz + r * ldo + col] = f2b(v);
        else
          ((float*)out)[(long)z * sOz + r * ldo + col] = v;
      }
    }
}

// ---------------------------------------------------------------------------
// fused QKV + V-transpose. block = (b*8+h, s-tile of 64, module).
// thread t: row sr = t>>2 (s = st*64+sr), col-quad cq = t&3 (dk = cq*16..+16).
// Q,K: per-head L2 norm via quad shfl reduce; written row-major.
// V: written TRANSPOSED to VT via LDS tile (no V buffer, no vtrans pass).
// ---------------------------------------------------------------------------
__global__ __launch_bounds__(256) void qkv_fused(
    const float* __restrict__ x, const float* __restrict__ EW,
    const u16* __restrict__ PB, u16* __restrict__ Q, u16* __restrict__ K,
    u16* __restrict__ VT, int m0, long mstride) {
  __shared__ float ews[3][4][64];
  __shared__ u16 vtile[64][72];
  const int bh = blockIdx.x;  // b*8+h
  const int st = blockIdx.y;
  const int mm = blockIdx.z;
  const int m = m0 + mm;
  const int b = bh >> 3, h = bh & 7;
  const int hoff = h * 64;
  const int t = threadIdx.x;
  if (t < 192) {
    int ty = t >> 6, dk = t & 63;
#pragma unroll
    for (int f = 0; f < 4; ++f)
      ews[ty][f][dk] = EW[(((long)(ty * 4 + m)) * 4 + f) * 512 + hoff + dk];
  }
  __syncthreads();
  const int sr = t >> 2, cq = t & 3;
  const int s = st * 64 + sr;
  const long rid = (long)b * 512 + s;
  const float* xr = x + rid * 7;
  const float xd = xr[3 + m], x0 = xr[0], x1 = xr[1], x2 = xr[2];
  const long obase = (long)mm * mstride + rid * 512 + hoff + cq * 16;

  float res[3][16];
#pragma unroll
  for (int ty = 0; ty < 3; ++ty) {
    const u16* pbp =
        PB + (((long)(ty * 4 + m)) * 512 + s) * 512 + hoff + cq * 16;
    short8 pbv0 = *(const short8*)pbp;
    short8 pbv1 = *(const short8*)(pbp + 8);
#pragma unroll
    for (int j = 0; j < 16; ++j) {
      int dk = cq * 16 + j;
      u16 pb = (u16)(j < 8 ? pbv0[j] : pbv1[j - 8]);
      res[ty][j] = xd * ews[ty][0][dk] + x0 * ews[ty][1][dk] +
                   x1 * ews[ty][2][dk] + x2 * ews[ty][3][dk] + b2f(pb);
    }
  }
  // Q, K: normalize over the head (64 dk = quad of lanes) and store
#pragma unroll
  for (int ty = 0; ty < 2; ++ty) {
    float ss = 0.f;
#pragma unroll
    for (int j = 0; j < 16; ++j) ss += res[ty][j] * res[ty][j];
    ss += __shfl_xor(ss, 1);
    ss += __shfl_xor(ss, 2);
    float sc = 1.f / fmaxf(sqrtf(ss), 1e-12f);
    u32 o[8];
#pragma unroll
    for (int jj = 0; jj < 8; ++jj)
      o[jj] = cvtpk(res[ty][2 * jj] * sc, res[ty][2 * jj + 1] * sc);
    u16* P = ty ? K : Q;
    *(u32x4*)&P[obase] = *(u32x4*)&o[0];
    *(u32x4*)&P[obase + 8] = *(u32x4*)&o[4];
  }
  // V into LDS tile
  {
    u32 o[8];
#pragma unroll
    for (int jj = 0; jj < 8; ++jj)
      o[jj] = cvtpk(res[2][2 * jj], res[2][2 * jj + 1]);
    *(short8*)&vtile[sr][cq * 16] = *(short8*)&o[0];
    *(short8*)&vtile[sr][cq * 16 + 8] = *(short8*)&o[4];
  }
  __syncthreads();
  // transposed V write: VT[(bh*64+dk)][st*64 + s']
  {
    int kr = t >> 2, sc2 = (t & 3) * 16;
    u16 tmp[16] __attribute__((aligned(16)));
#pragma unroll
    for (int j = 0; j < 16; ++j) tmp[j] = vtile[sc2 + j][kr];
    long gdst =
        (long)mm * mstride + ((long)bh * 64 + kr) * 512 + st * 64 + sc2;
    *(short8*)&VT[gdst] = *(short8*)&tmp[0];
    *(short8*)&VT[gdst + 8] = *(short8*)&tmp[8];
  }
}

// ---------------------------------------------------------------------------
// flash attention, max-free, 32x32 swapped-operand form.
// S^T = mfma32(K_frag, Q_frag); P^T packed via v_cvt_pk + shfl_xor(32);
// O^T = mfma32(VT_frag, PT_frag); row-sum l via ones-MFMA (matrix pipe).
// ---------------------------------------------------------------------------
__global__ __launch_bounds__(256, 4) void attn_kernel(
    const u16* __restrict__ Qg, const u16* __restrict__ Kg,
    const u16* __restrict__ VTg, u16* __restrict__ ctxg, long mstride) {
  __shared__ u16 Kb[2][64][64];
  __shared__ u16 Vb[2][64][64];
  const u16* Q = Qg + (long)blockIdx.z * mstride;
  const u16* K = Kg + (long)blockIdx.z * mstride;
  const u16* VT = VTg + (long)blockIdx.z * mstride;
  u16* ctx = ctxg + (long)blockIdx.z * mstride;
  const int bh = blockIdx.x;  // b*8+h
  const int qb = blockIdx.y;
  const int b = bh >> 3, h = bh & 7;
  const int tid = threadIdx.x, w = tid >> 6, l = tid & 63;
  const int lq = l & 31, hi = l >> 5, l7 = l & 7;
  const long rowbase = (long)b * 512;
  const int hoff = h * 64;
  const int rw = l >> 3, gch = (l & 7) ^ rw;

  short8 qf[4];
  {
    const u16* qrow =
        Q + (rowbase + qb * 128 + w * 32 + lq) * 512 + hoff + hi * 8;
#pragma unroll
    for (int dc = 0; dc < 4; ++dc) qf[dc] = *(const short8*)(qrow + dc * 16);
  }

  short8 ones;
#pragma unroll
  for (int i = 0; i < 8; ++i) ones[i] = (short)0x3F80;  // bf16 1.0

  f32x16 o_acc[2] = {};
  f32x16 l_acc = {};

  const u16* Kgbase = K + rowbase * 512 + hoff + gch * 8;
  const u16* Vgbase = VT + (long)bh * 64 * 512 + gch * 8;

#define STAGE(bf, kt)                                                         \
  {                                                                           \
    _Pragma("unroll") for (int i = 0; i < 2; ++i) {                           \
      int rr = w * 16 + i * 8;                                                \
      gload16(Kgbase + (long)((kt)*64 + rr + rw) * 512, &Kb[bf][rr][0]);      \
      gload16(Vgbase + (long)(rr + rw) * 512 + (kt)*64, &Vb[bf][rr][0]);      \
    }                                                                         \
  }

  STAGE(0, 0);
  __syncthreads();

  for (int kt = 0; kt < 8; ++kt) {
    const int cur = kt & 1;
    if (kt < 7) STAGE(cur ^ 1, kt + 1);  // async prefetch in flight
    __builtin_amdgcn_s_setprio(1);
#pragma unroll
    for (int ktile = 0; ktile < 2; ++ktile) {
      f32x16 s = {};
#pragma unroll
      for (int dc = 0; dc < 4; ++dc) {
        short8 kf = *(const short8*)((const char*)&Kb[cur][ktile * 32 + lq][0] +
                                     (((dc * 2 + hi) ^ l7) * 16));
        s = mfma32(kf, qf[dc], s);
      }
      // P = exp(S) (|S| <= ~1), pack with HW cvt_pk
      float p[16];
#pragma unroll
      for (int r = 0; r < 16; ++r) p[r] = __expf(s[r]);
      u32 A0 = cvtpk(p[0], p[1]), A1 = cvtpk(p[2], p[3]);
      u32 A2 = cvtpk(p[4], p[5]), A3 = cvtpk(p[6], p[7]);
      u32 A4 = cvtpk(p[8], p[9]), A5 = cvtpk(p[10], p[11]);
      u32 A6 = cvtpk(p[12], p[13]), A7 = cvtpk(p[14], p[15]);
      u32 pA0 = __shfl_xor(A0, 32), pA1 = __shfl_xor(A1, 32);
      u32 pA2 = __shfl_xor(A2, 32), pA3 = __shfl_xor(A3, 32);
      u32 pA4 = __shfl_xor(A4, 32), pA5 = __shfl_xor(A5, 32);
      u32 pA6 = __shfl_xor(A6, 32), pA7 = __shfl_xor(A7, 32);
      u32x4 f0 = {hi ? pA2 : A0, hi ? pA3 : A1, hi ? A2 : pA0, hi ? A3 : pA1};
      u32x4 f1 = {hi ? pA6 : A4, hi ? pA7 : A5, hi ? A6 : pA4, hi ? A7 : pA5};
      short8 bf0 = __builtin_bit_cast(short8, f0);
      short8 bf1 = __builtin_bit_cast(short8, f1);
#pragma unroll
      for (int kk2 = 0; kk2 < 2; ++kk2) {
        const int kc = ktile * 2 + kk2;
        short8 pb = kk2 ? bf1 : bf0;
        l_acc = mfma32(ones, pb, l_acc);  // row-sum on matrix pipe
#pragma unroll
        for (int dt = 0; dt < 2; ++dt) {
          short8 vf =
              *(const short8*)((const char*)&Vb[cur][dt * 32 + lq][0] +
                               (((kc * 2 + hi) ^ l7) * 16));
          o_acc[dt] = mfma32(vf, pb, o_acc[dt]);
        }
      }
    }
    __builtin_amdgcn_s_setprio(0);
    __syncthreads();  // drains prefetch vmcnt + frees cur buffer
  }
#undef STAGE
  const float inv = 1.f / l_acc[0];
  u16* crow = ctx + (rowbase + qb * 128 + w * 32 + lq) * 512 + hoff + hi * 4;
#pragma unroll
  for (int dt = 0; dt < 2; ++dt)
#pragma unroll
    for (int rq = 0; rq < 4; ++rq) {
      u32 w0 = cvtpk(o_acc[dt][rq * 4 + 0] * inv, o_acc[dt][rq * 4 + 1] * inv);
      u32 w1 = cvtpk(o_acc[dt][rq * 4 + 2] * inv, o_acc[dt][rq * 4 + 3] * inv);
      u32x2 pr = {w0, w1};
      *(u32x2*)&crow[dt * 32 + rq * 8] = pr;
    }
}

// ---------------------------------------------------------------------------
// t[r][j] = sum_m ctx_m[r][:] . WEFFT[m][j][:]
// ---------------------------------------------------------------------------
__global__ __launch_bounds__(64) void t_gemm(const u16* __restrict__ ctx4,
                                             const u16* __restrict__ WEFFT,
                                             float* __restrict__ t) {
  const int l = threadIdx.x;
  const long r0 = (long)blockIdx.x * 16;
  f32x4 acc = {};
#pragma unroll
  for (int m = 0; m < 4; ++m) {
    const u16* A =
        ctx4 + (long)m * 8388608 + (r0 + (l & 15)) * 512 + (l >> 4) * 8;
    const u16* Bb = WEFFT + m * 8192 + (l & 15) * 512 + (l >> 4) * 8;
#pragma unroll
    for (int kt = 0; kt < 16; ++kt) {
      short8 af = *(const short8*)(A + kt * 32);
      short8 bf = *(const short8*)(Bb + kt * 32);
      acc = mfma16(af, bf, acc);
    }
  }
#pragma unroll
  for (int q = 0; q < 4; ++q)
    t[(r0 + (l >> 4) * 4 + q) * 16 + (l & 15)] = acc[q];
}

// ---------------------------------------------------------------------------
// tail1: c1 (from t) + elu -> conv2 + elu + pool -> flat (global, f32)
// ---------------------------------------------------------------------------
__global__ __launch_bounds__(256) void tail1_kernel(
    const float* __restrict__ t, const float* __restrict__ bias_t,
    const float* __restrict__ b1, const float* __restrict__ w2,
    const float* __restrict__ b2, float* __restrict__ flat) {
  __shared__ float ts[512][16];
  __shared__ float c1s[5][512];
  int b = blockIdx.x, tid = threadIdx.x;
  const float4* tsrc = (const float4*)(t + (long)b * 8192);
  float4* tdst = (float4*)&ts[0][0];
#pragma unroll
  for (int i = 0; i < 8; ++i) tdst[tid + i * 256] = tsrc[tid + i * 256];
  __syncthreads();
#pragma unroll
  for (int i = 0; i < 10; ++i) {
    int idx = tid + i * 256;  // 0..2559
    int o = idx >> 9, s = idx & 511;
    float a = b1[o];
#pragma unroll
    for (int k = 0; k < 3; ++k) {
      int ss = s + k - 1;
      if (ss >= 0 && ss < 512) a += ts[ss][o * 3 + k] + bias_t[o * 3 + k];
    }
    c1s[o][s] = eluf(a);
  }
  __syncthreads();
#pragma unroll
  for (int i = 0; i < 2; ++i) {
    int r = tid + i * 256;  // 0..511
    int o = r >> 8, sp = r & 255;
    float mx = -1e30f;
#pragma unroll
    for (int sd = 0; sd < 2; ++sd) {
      int s = sp * 2 + sd;
      float a = b2[o];
#pragma unroll
      for (int ic = 0; ic < 5; ++ic)
#pragma unroll
        for (int k = 0; k < 3; ++k) {
          int ss = s + k - 1;
          if (ss >= 0 && ss < 512) a += c1s[ic][ss] * w2[(o * 5 + ic) * 3 + k];
        }
      mx = fmaxf(mx, eluf(a));
    }
    flat[(long)b * 512 + r] = mx;
  }
}

// ---------------------------------------------------------------------------
// head: fc1+fc2+fc3+LN; 1024 threads, split-K partials
// ---------------------------------------------------------------------------
__global__ __launch_bounds__(1024) void head_kernel(
    const float* __restrict__ flat, const float* __restrict__ fw1,
    const float* __restrict__ fb1, const float* __restrict__ fw2,
    const float* __restrict__ fb2, const float* __restrict__ fw3,
    const float* __restrict__ fb3, const float* __restrict__ g,
    const float* __restrict__ be, float* __restrict__ out) {
  __shared__ float xb[512];
  __shared__ float z1p[4][256];
  __shared__ float z1[256];
  __shared__ float z2p[2][128];
  __shared__ float z2[128];
  __shared__ float z3[96];
  int b = blockIdx.x, t = threadIdx.x;
  if (t < 512) xb[t] = flat[(long)b * 512 + t];
  __syncthreads();
  {
    int o = t & 255, part = t >> 8;
    float a = 0.f;
    const float* wp = fw1 + (long)part * 128 * 256 + o;
    const float* xp = xb + part * 128;
#pragma unroll 8
    for (int i = 0; i < 128; ++i) a += xp[i] * wp[i * 256];
    z1p[part][o] = a;
  }
  __syncthreads();
  if (t < 256)
    z1[t] = eluf(fb1[t] + z1p[0][t] + z1p[1][t] + z1p[2][t] + z1p[3][t]);
  __syncthreads();
  if (t < 256) {
    int o = t & 127, part = t >> 7;
    float a = 0.f;
    const float* wp = fw2 + (long)part * 128 * 128 + o;
    const float* xp = z1 + part * 128;
#pragma unroll 8
    for (int i = 0; i < 128; ++i) a += xp[i] * wp[i * 128];
    z2p[part][o] = a;
  }
  __syncthreads();
  if (t < 128) z2[t] = eluf(fb2[t] + z2p[0][t] + z2p[1][t]);
  __syncthreads();
  if (t < 96) {
    float a = fb3[t];
#pragma unroll 8
    for (int i = 0; i < 128; ++i) a += z2[i] * fw3[i * 96 + t];
    z3[t] = a;
  }
  __syncthreads();
  if (t < 96) {
    float mu = 0.f;
    for (int j = 0; j < 96; ++j) mu += z3[j];
    mu *= (1.f / 96.f);
    float sq = 0.f;
    for (int j = 0; j < 96; ++j) {
      float d = z3[j] - mu;
      sq += d * d;
    }
    float var = sq * (1.f / 96.f);
    out[b * 96 + t] = (z3[t] - mu) / sqrtf(var + 1e-5f) * g[t] + be[t];
  }
}

// ---------------------------------------------------------------------------
extern "C" void kernel_launch(void* const* d_in, const int* in_sizes, int n_in,
                              void* d_out, int out_size, void* d_ws,
                              size_t ws_size, hipStream_t stream) {
  (void)in_sizes; (void)n_in; (void)out_size;
  const float* x    = (const float*)d_in[0];
  const float* embW = (const float*)d_in[1];
  const float* embB = (const float*)d_in[2];
  const float* Wq   = (const float*)d_in[3];
  const float* bq   = (const float*)d_in[4];
  const float* Wk   = (const float*)d_in[5];
  const float* bk   = (const float*)d_in[6];
  const float* Wv   = (const float*)d_in[7];
  const float* bv   = (const float*)d_in[8];
  const float* Wo   = (const float*)d_in[9];
  const float* bo   = (const float*)d_in[10];
  const float* c1w  = (const float*)d_in[11];
  const float* c1b  = (const float*)d_in[12];
  const float* c2w  = (const float*)d_in[13];
  const float* c2b  = (const float*)d_in[14];
  const float* f1w  = (const float*)d_in[15];
  const float* f1b  = (const float*)d_in[16];
  const float* f2w  = (const float*)d_in[17];
  const float* f2b_ = (const float*)d_in[18];
  const float* f3w  = (const float*)d_in[19];
  const float* f3b  = (const float*)d_in[20];
  const float* lng  = (const float*)d_in[21];
  const float* lnb  = (const float*)d_in[22];
  float* out = (float*)d_out;

  char* p = (char*)d_ws;
  const size_t NEED = 182181952;
  if (ws_size < NEED) return;
  const long MS = 8388608;  // per-module stride in u16 elements (16 MB)

  u16*   A_pe    = (u16*)(p + 0);
  u16*   WTqkv   = (u16*)(p + 524288);
  float* pb_bias = (float*)(p + 6815744);
  float* EW      = (float*)(p + 6840320);
  u16*   PB      = (u16*)(p + 6938624);
  u16*   Q2      = (u16*)(p + 13230080);
  u16*   K2      = (u16*)(p + 46784512);
  u16*   VT2     = (u16*)(p + 80338944);
  u16*   ctx4    = (u16*)(p + 113893376);
  u16*   WEFFT   = (u16*)(p + 181002240);
  float* bias_t  = (float*)(p + 181067776);
  float* t_buf   = (float*)(p + 181067840);
  float* flat    = (float*)(p + 182116416);

  prep_pe<<<536, 256, 0, stream>>>(embB, bq, bk, bv, A_pe, pb_bias);
  transw<<<dim3(12, 8, 8), 256, 0, stream>>>(Wq, Wk, Wv, WTqkv);
  ew_kernel<<<12, 256, 0, stream>>>(Wq, Wk, Wv, embW, EW);
  weff_kernel<<<2049, 64, 0, stream>>>(Wo, bo, c1w, WEFFT, bias_t);
  gemm_bt<true><<<dim3(4, 4, 12), 256, 0, stream>>>(
      A_pe, 0, 512, WTqkv, pb_bias, (void*)PB, 262144, 512);

  for (int gp = 0; gp < 2; ++gp) {
    qkv_fused<<<dim3(256, 8, 2), 256, 0, stream>>>(x, EW, PB, Q2, K2, VT2,
                                                   gp * 2, MS);
    attn_kernel<<<dim3(256, 4, 2), 256, 0, stream>>>(
        Q2, K2, VT2, ctx4 + (long)gp * 2 * MS, MS);
  }

  t_gemm<<<1024, 64, 0, stream>>>(ctx4, WEFFT, t_buf);
  tail1_kernel<<<32, 256, 0, stream>>>(t_buf, bias_t, c1b, c2w, c2b, flat);
  head_kernel<<<32, 1024, 0, stream>>>(flat, f1w, f1b, f2w, f2b_, f3w, f3b,
                                       lng, lnb, out);
}

// Round 8
// 267.071 us; speedup vs baseline: 1.5272x; 1.0534x over previous
//
#include <hip/hip_runtime.h>
#include <math.h>

typedef unsigned short u16;
typedef unsigned int u32;
typedef __attribute__((ext_vector_type(8))) short short8;
typedef __attribute__((ext_vector_type(4))) float f32x4;
typedef __attribute__((ext_vector_type(16))) float f32x16;
typedef __attribute__((ext_vector_type(4))) u32 u32x4;
typedef __attribute__((ext_vector_type(2))) u32 u32x2;

__device__ inline u16 f2b(float f) {
  u32 u = __builtin_bit_cast(u32, f);
  u32 r = u + 0x7fffu + ((u >> 16) & 1u);
  return (u16)(r >> 16);
}
__device__ inline float b2f(u16 b) {
  return __builtin_bit_cast(float, (u32)b << 16);
}
// HW packed f32->bf16 (RTNE), 1 instruction for 2 values
__device__ inline u32 cvtpk(float lo, float hi) {
  u32 r;
  asm("v_cvt_pk_bf16_f32 %0, %1, %2" : "=v"(r) : "v"(lo), "v"(hi));
  return r;
}
__device__ inline float eluf(float x) { return x > 0.f ? x : expf(x) - 1.f; }

__device__ inline f32x4 mfma16(short8 a, short8 b, f32x4 c) {
  return __builtin_amdgcn_mfma_f32_16x16x32_bf16(a, b, c, 0, 0, 0);
}
__device__ inline f32x16 mfma32(short8 a, short8 b, f32x16 c) {
  return __builtin_amdgcn_mfma_f32_32x32x16_bf16(a, b, c, 0, 0, 0);
}
__device__ inline void gload16(const u16* g, u16* l) {
  __builtin_amdgcn_global_load_lds((__attribute__((address_space(1))) void*)(g),
                                   (__attribute__((address_space(3))) void*)(l),
                                   16, 0, 0);
}

// ---------------------------------------------------------------------------
// prep_misc: fused prep_pe + pb_bias gather + EW + WEFF/bias_t
//   bid [0,512):    A_pe rows (PE + emb_b, bf16)
//   bid [512,536):  pb_bias gather
//   bid [536,548):  EW (z = bid-536)
//   bid [548,1061): WEFF (4 waves = 4 d-rows) ; block 1060 wave0 = bias_t
// ---------------------------------------------------------------------------
__global__ __launch_bounds__(256) void prep_misc(
    const float* __restrict__ emb_b, const float* __restrict__ bq,
    const float* __restrict__ bk, const float* __restrict__ bv,
    const float* __restrict__ Wq, const float* __restrict__ Wk,
    const float* __restrict__ Wv, const float* __restrict__ embW,
    const float* __restrict__ Wo, const float* __restrict__ bo,
    const float* __restrict__ w1, u16* __restrict__ A_pe,
    float* __restrict__ pb_bias, float* __restrict__ EW,
    u16* __restrict__ WEFFT, float* __restrict__ bias_t) {
  __shared__ float smem[2048];
  const int bid = blockIdx.x, t = threadIdx.x;
  if (bid < 512) {
    int s = bid;
    float div = expf((2.f * t) * (-9.210340371976184f / 512.f));
    float arg = (float)s * div;
    A_pe[s * 512 + 2 * t] = f2b(sinf(arg) + emb_b[2 * t]);
    A_pe[s * 512 + 2 * t + 1] = f2b(cosf(arg) + emb_b[2 * t + 1]);
  } else if (bid < 536) {
    int i = (bid - 512) * 256 + t;  // 0..6143
    int z = i >> 9, e = i & 511;
    int ty = z >> 2, m = z & 3;
    const float* bp = (ty == 0) ? bq : (ty == 1) ? bk : bv;
    pb_bias[i] = bp[m * 512 + e];
  } else if (bid < 548) {
    int z = bid - 536;
    const float* W =
        ((z < 4) ? Wq : (z < 8) ? Wk : Wv) + (long)(z & 3) * 262144;
#pragma unroll
    for (int i = 0; i < 8; ++i) smem[t + i * 256] = embW[t + i * 256];
    __syncthreads();
    float a[4][2] = {};
    for (int d = 0; d < 512; ++d) {
      float w0 = W[(long)d * 512 + t];
      float w1v = W[(long)d * 512 + t + 256];
#pragma unroll
      for (int f = 0; f < 4; ++f) {
        float e = smem[f * 512 + d];
        a[f][0] += e * w0;
        a[f][1] += e * w1v;
      }
    }
#pragma unroll
    for (int f = 0; f < 4; ++f) {
      EW[((long)z * 4 + f) * 512 + t] = a[f][0];
      EW[((long)z * 4 + f) * 512 + t + 256] = a[f][1];
    }
  } else {
    const int wb = bid - 548;  // 0..512
    const int w = t >> 6, l = t & 63;
    if (wb < 512) {
      int idx = wb * 4 + w;  // 0..2047
      int m = idx >> 9, d = idx & 511;
      const float* wrow = Wo + ((long)m * 512 + d) * 512;
      float a[15] = {};
#pragma unroll
      for (int i = 0; i < 8; ++i) {
        int e = l * 8 + i;
        float wv = wrow[e];
#pragma unroll
        for (int o = 0; o < 5; ++o)
#pragma unroll
          for (int k = 0; k < 3; ++k)
            a[o * 3 + k] += wv * w1[((long)o * 2048 + m * 512 + e) * 3 + k];
      }
#pragma unroll
      for (int j = 0; j < 15; ++j) {
        float v = a[j];
        for (int o = 1; o < 64; o <<= 1) v += __shfl_xor(v, o);
        if (l == 0) WEFFT[((long)m * 16 + j) * 512 + d] = f2b(v);
      }
      if (l == 0) WEFFT[((long)m * 16 + 15) * 512 + d] = 0;
    } else if (w == 0) {
      float a[15] = {};
      for (int c = l; c < 2048; c += 64) {
        float bv = bo[c];
#pragma unroll
        for (int o = 0; o < 5; ++o)
#pragma unroll
          for (int k = 0; k < 3; ++k)
            a[o * 3 + k] += bv * w1[((long)o * 2048 + c) * 3 + k];
      }
#pragma unroll
      for (int j = 0; j < 15; ++j) {
        float v = a[j];
        for (int o = 1; o < 64; o <<= 1) v += __shfl_xor(v, o);
        if (l == 0) bias_t[j] = v;
      }
      if (l == 0) bias_t[15] = 0.f;
    }
  }
}

// ---------------------------------------------------------------------------
// transpose the 12 QKV weight matrices -> bf16 [e][d]
// ---------------------------------------------------------------------------
__global__ __launch_bounds__(256) void transw(
    const float* __restrict__ Wq, const float* __restrict__ Wk,
    const float* __restrict__ Wv, u16* __restrict__ WTqkv) {
  __shared__ float tile[64][65];
  int mid = blockIdx.x;
  const float* W = ((mid < 4) ? Wq : (mid < 8) ? Wk : Wv) + (long)(mid & 3) * 262144;
  u16* WT = WTqkv + (long)mid * 262144;
  int d0 = blockIdx.y * 64, e0 = blockIdx.z * 64;
  int t = threadIdx.x;
  int dr = t >> 2, ec = (t & 3) * 16;
#pragma unroll
  for (int j = 0; j < 16; j += 4) {
    float4 v = *(const float4*)&W[(long)(d0 + dr) * 512 + e0 + ec + j];
    tile[dr][ec + j] = v.x;
    tile[dr][ec + j + 1] = v.y;
    tile[dr][ec + j + 2] = v.z;
    tile[dr][ec + j + 3] = v.w;
  }
  __syncthreads();
  int er = t >> 2, dc = (t & 3) * 16;
  u16 tmp[16] __attribute__((aligned(16)));
#pragma unroll
  for (int j = 0; j < 16; ++j) tmp[j] = f2b(tile[dc + j][er]);
  *(short8*)&WT[(long)(e0 + er) * 512 + d0 + dc] = *(short8*)&tmp[0];
  *(short8*)&WT[(long)(e0 + er) * 512 + d0 + dc + 8] = *(short8*)&tmp[8];
}

// ---------------------------------------------------------------------------
// generic bf16 GEMM  C[r][c] = sum_k A[r][k] * BT[c][k] + bias[c]
// ---------------------------------------------------------------------------
template <bool OBF>
__global__ __launch_bounds__(256) void gemm_bt(
    const u16* __restrict__ A, long sAz, int lda, const u16* __restrict__ BT,
    const float* __restrict__ bias, void* __restrict__ out, long sOz, int ldo) {
  __shared__ u16 As[128 * 32];
  __shared__ u16 Bs[128 * 32];
  const int z = blockIdx.z;
  const int tid = threadIdx.x, w = tid >> 6, l = tid & 63;
  const long row0 = (long)blockIdx.y * 128;
  const u16* Ab = A + (long)z * sAz + row0 * lda;
  const u16* Bb = BT + (long)z * 262144 + (long)blockIdx.x * 128 * 512;
  const u16* ga = Ab + (long)(w * 32 + (l >> 2)) * lda + (l & 3) * 8;
  const u16* gb = Bb + (long)(w * 32 + (l >> 2)) * 512 + (l & 3) * 8;
  u16* lA = As + w * 32 * 32;
  u16* lB = Bs + w * 32 * 32;
  f32x4 acc[4][4] = {};
  const int wr = (w >> 1) * 64, wc = (w & 1) * 64;
  for (int kt = 0; kt < 16; ++kt) {
    gload16(ga + kt * 32, lA);
    gload16(ga + kt * 32 + 16 * lda, lA + 16 * 32);
    gload16(gb + kt * 32, lB);
    gload16(gb + kt * 32 + 16 * 512, lB + 16 * 32);
    __syncthreads();
    short8 af[4], bf[4];
#pragma unroll
    for (int i = 0; i < 4; ++i)
      af[i] = *(const short8*)&As[(wr + i * 16 + (l & 15)) * 32 + (l >> 4) * 8];
#pragma unroll
    for (int i = 0; i < 4; ++i)
      bf[i] = *(const short8*)&Bs[(wc + i * 16 + (l & 15)) * 32 + (l >> 4) * 8];
#pragma unroll
    for (int i = 0; i < 4; ++i)
#pragma unroll
      for (int j = 0; j < 4; ++j) acc[i][j] = mfma16(af[i], bf[j], acc[i][j]);
    __syncthreads();
  }
  const int colB = blockIdx.x * 128 + wc;
#pragma unroll
  for (int i = 0; i < 4; ++i)
#pragma unroll
    for (int j = 0; j < 4; ++j) {
      int col = colB + j * 16 + (l & 15);
      float bb = bias[(long)z * 512 + col];
#pragma unroll
      for (int q = 0; q < 4; ++q) {
        long r = row0 + wr + i * 16 + (l >> 4) * 4 + q;
        float v = acc[i][j][q] + bb;
        if (OBF)
          ((u16*)out)[(long)z * sOz + r * ldo + col] = f2b(v);
        else
          ((float*)out)[(long)z * sOz + r * ldo + col] = v;
      }
    }
}

// ---------------------------------------------------------------------------
// fused QKV + V-transpose. block = (b*8+h, s-tile of 64, module).
// ---------------------------------------------------------------------------
__global__ __launch_bounds__(256) void qkv_fused(
    const float* __restrict__ x, const float* __restrict__ EW,
    const u16* __restrict__ PB, u16* __restrict__ Q, u16* __restrict__ K,
    u16* __restrict__ VT, int m0, long mstride) {
  __shared__ float ews[3][4][64];
  __shared__ u16 vtile[64][72];
  const int bh = blockIdx.x;  // b*8+h
  const int st = blockIdx.y;
  const int mm = blockIdx.z;
  const int m = m0 + mm;
  const int b = bh >> 3, h = bh & 7;
  const int hoff = h * 64;
  const int t = threadIdx.x;
  if (t < 192) {
    int ty = t >> 6, dk = t & 63;
#pragma unroll
    for (int f = 0; f < 4; ++f)
      ews[ty][f][dk] = EW[(((long)(ty * 4 + m)) * 4 + f) * 512 + hoff + dk];
  }
  __syncthreads();
  const int sr = t >> 2, cq = t & 3;
  const int s = st * 64 + sr;
  const long rid = (long)b * 512 + s;
  const float* xr = x + rid * 7;
  const float xd = xr[3 + m], x0 = xr[0], x1 = xr[1], x2 = xr[2];
  const long obase = (long)mm * mstride + rid * 512 + hoff + cq * 16;

  float res[3][16];
#pragma unroll
  for (int ty = 0; ty < 3; ++ty) {
    const u16* pbp =
        PB + (((long)(ty * 4 + m)) * 512 + s) * 512 + hoff + cq * 16;
    short8 pbv0 = *(const short8*)pbp;
    short8 pbv1 = *(const short8*)(pbp + 8);
#pragma unroll
    for (int j = 0; j < 16; ++j) {
      int dk = cq * 16 + j;
      u16 pb = (u16)(j < 8 ? pbv0[j] : pbv1[j - 8]);
      res[ty][j] = xd * ews[ty][0][dk] + x0 * ews[ty][1][dk] +
                   x1 * ews[ty][2][dk] + x2 * ews[ty][3][dk] + b2f(pb);
    }
  }
#pragma unroll
  for (int ty = 0; ty < 2; ++ty) {
    float ss = 0.f;
#pragma unroll
    for (int j = 0; j < 16; ++j) ss += res[ty][j] * res[ty][j];
    ss += __shfl_xor(ss, 1);
    ss += __shfl_xor(ss, 2);
    float sc = 1.f / fmaxf(sqrtf(ss), 1e-12f);
    u32 o[8];
#pragma unroll
    for (int jj = 0; jj < 8; ++jj)
      o[jj] = cvtpk(res[ty][2 * jj] * sc, res[ty][2 * jj + 1] * sc);
    u16* P = ty ? K : Q;
    *(u32x4*)&P[obase] = *(u32x4*)&o[0];
    *(u32x4*)&P[obase + 8] = *(u32x4*)&o[4];
  }
  {
    u32 o[8];
#pragma unroll
    for (int jj = 0; jj < 8; ++jj)
      o[jj] = cvtpk(res[2][2 * jj], res[2][2 * jj + 1]);
    *(short8*)&vtile[sr][cq * 16] = *(short8*)&o[0];
    *(short8*)&vtile[sr][cq * 16 + 8] = *(short8*)&o[4];
  }
  __syncthreads();
  {
    int kr = t >> 2, sc2 = (t & 3) * 16;
    u16 tmp[16] __attribute__((aligned(16)));
#pragma unroll
    for (int j = 0; j < 16; ++j) tmp[j] = vtile[sc2 + j][kr];
    long gdst =
        (long)mm * mstride + ((long)bh * 64 + kr) * 512 + st * 64 + sc2;
    *(short8*)&VT[gdst] = *(short8*)&tmp[0];
    *(short8*)&VT[gdst + 8] = *(short8*)&tmp[8];
  }
}

// ---------------------------------------------------------------------------
// flash attention, max-free, 32x32 swapped-operand; counted-vmcnt pipeline:
// STAGE(kt+1) -> s_waitcnt vmcnt(4) (tile kt ready, kt+1 stays in flight) ->
// raw s_barrier -> compute -> raw s_barrier (buffer-overwrite guard).
// Never drains vmcnt to 0 inside the loop (T4).
// ---------------------------------------------------------------------------
__global__ __launch_bounds__(256, 4) void attn_kernel(
    const u16* __restrict__ Qg, const u16* __restrict__ Kg,
    const u16* __restrict__ VTg, u16* __restrict__ ctxg, long mstride) {
  __shared__ u16 Kb[2][64][64];
  __shared__ u16 Vb[2][64][64];
  const u16* Q = Qg + (long)blockIdx.z * mstride;
  const u16* K = Kg + (long)blockIdx.z * mstride;
  const u16* VT = VTg + (long)blockIdx.z * mstride;
  u16* ctx = ctxg + (long)blockIdx.z * mstride;
  const int bh = blockIdx.x;  // b*8+h
  const int qb = blockIdx.y;
  const int b = bh >> 3, h = bh & 7;
  const int tid = threadIdx.x, w = tid >> 6, l = tid & 63;
  const int lq = l & 31, hi = l >> 5, l7 = l & 7;
  const long rowbase = (long)b * 512;
  const int hoff = h * 64;
  const int rw = l >> 3, gch = (l & 7) ^ rw;

  short8 qf[4];
  {
    const u16* qrow =
        Q + (rowbase + qb * 128 + w * 32 + lq) * 512 + hoff + hi * 8;
#pragma unroll
    for (int dc = 0; dc < 4; ++dc) qf[dc] = *(const short8*)(qrow + dc * 16);
  }

  short8 ones;
#pragma unroll
  for (int i = 0; i < 8; ++i) ones[i] = (short)0x3F80;  // bf16 1.0

  f32x16 o_acc[2] = {};
  f32x16 l_acc = {};

  const u16* Kgbase = K + rowbase * 512 + hoff + gch * 8;
  const u16* Vgbase = VT + (long)bh * 64 * 512 + gch * 8;

#define STAGE(bf, kt)                                                         \
  {                                                                           \
    _Pragma("unroll") for (int i = 0; i < 2; ++i) {                           \
      int rr = w * 16 + i * 8;                                                \
      gload16(Kgbase + (long)((kt)*64 + rr + rw) * 512, &Kb[bf][rr][0]);      \
      gload16(Vgbase + (long)(rr + rw) * 512 + (kt)*64, &Vb[bf][rr][0]);      \
    }                                                                         \
  }

  STAGE(0, 0);  // 4 loads in flight

  for (int kt = 0; kt < 8; ++kt) {
    const int cur = kt & 1;
    if (kt < 7) {
      STAGE(cur ^ 1, kt + 1);  // issue next tile (4 more loads)
      asm volatile("s_waitcnt vmcnt(4)" ::: "memory");  // tile kt ready (mine)
    } else {
      asm volatile("s_waitcnt vmcnt(0)" ::: "memory");
    }
    __builtin_amdgcn_s_barrier();  // all waves' tile kt in LDS
    __builtin_amdgcn_sched_barrier(0);
    __builtin_amdgcn_s_setprio(1);
#pragma unroll
    for (int ktile = 0; ktile < 2; ++ktile) {
      f32x16 s = {};
#pragma unroll
      for (int dc = 0; dc < 4; ++dc) {
        short8 kf = *(const short8*)((const char*)&Kb[cur][ktile * 32 + lq][0] +
                                     (((dc * 2 + hi) ^ l7) * 16));
        s = mfma32(kf, qf[dc], s);
      }
      float p[16];
#pragma unroll
      for (int r = 0; r < 16; ++r) p[r] = __expf(s[r]);
      u32 A0 = cvtpk(p[0], p[1]), A1 = cvtpk(p[2], p[3]);
      u32 A2 = cvtpk(p[4], p[5]), A3 = cvtpk(p[6], p[7]);
      u32 A4 = cvtpk(p[8], p[9]), A5 = cvtpk(p[10], p[11]);
      u32 A6 = cvtpk(p[12], p[13]), A7 = cvtpk(p[14], p[15]);
      u32 pA0 = __shfl_xor(A0, 32), pA1 = __shfl_xor(A1, 32);
      u32 pA2 = __shfl_xor(A2, 32), pA3 = __shfl_xor(A3, 32);
      u32 pA4 = __shfl_xor(A4, 32), pA5 = __shfl_xor(A5, 32);
      u32 pA6 = __shfl_xor(A6, 32), pA7 = __shfl_xor(A7, 32);
      u32x4 f0 = {hi ? pA2 : A0, hi ? pA3 : A1, hi ? A2 : pA0, hi ? A3 : pA1};
      u32x4 f1 = {hi ? pA6 : A4, hi ? pA7 : A5, hi ? A6 : pA4, hi ? A7 : pA5};
      short8 bf0 = __builtin_bit_cast(short8, f0);
      short8 bf1 = __builtin_bit_cast(short8, f1);
#pragma unroll
      for (int kk2 = 0; kk2 < 2; ++kk2) {
        const int kc = ktile * 2 + kk2;
        short8 pb = kk2 ? bf1 : bf0;
        l_acc = mfma32(ones, pb, l_acc);  // row-sum on matrix pipe
#pragma unroll
        for (int dt = 0; dt < 2; ++dt) {
          short8 vf =
              *(const short8*)((const char*)&Vb[cur][dt * 32 + lq][0] +
                               (((kc * 2 + hi) ^ l7) * 16));
          o_acc[dt] = mfma32(vf, pb, o_acc[dt]);
        }
      }
    }
    __builtin_amdgcn_s_setprio(0);
    __builtin_amdgcn_sched_barrier(0);
    __builtin_amdgcn_s_barrier();  // all waves done reading cur (no drain)
    __builtin_amdgcn_sched_barrier(0);
  }
#undef STAGE
  const float inv = 1.f / l_acc[0];
  u16* crow = ctx + (rowbase + qb * 128 + w * 32 + lq) * 512 + hoff + hi * 4;
#pragma unroll
  for (int dt = 0; dt < 2; ++dt)
#pragma unroll
    for (int rq = 0; rq < 4; ++rq) {
      u32 w0 = cvtpk(o_acc[dt][rq * 4 + 0] * inv, o_acc[dt][rq * 4 + 1] * inv);
      u32 w1 = cvtpk(o_acc[dt][rq * 4 + 2] * inv, o_acc[dt][rq * 4 + 3] * inv);
      u32x2 pr = {w0, w1};
      *(u32x2*)&crow[dt * 32 + rq * 8] = pr;
    }
}

// ---------------------------------------------------------------------------
// t[r][j] = sum_m ctx_m[r][:] . WEFFT[m][j][:]
// ---------------------------------------------------------------------------
__global__ __launch_bounds__(64) void t_gemm(const u16* __restrict__ ctx4,
                                             const u16* __restrict__ WEFFT,
                                             float* __restrict__ t) {
  const int l = threadIdx.x;
  const long r0 = (long)blockIdx.x * 16;
  f32x4 acc = {};
#pragma unroll
  for (int m = 0; m < 4; ++m) {
    const u16* A =
        ctx4 + (long)m * 8388608 + (r0 + (l & 15)) * 512 + (l >> 4) * 8;
    const u16* Bb = WEFFT + m * 8192 + (l & 15) * 512 + (l >> 4) * 8;
#pragma unroll
    for (int kt = 0; kt < 16; ++kt) {
      short8 af = *(const short8*)(A + kt * 32);
      short8 bf = *(const short8*)(Bb + kt * 32);
      acc = mfma16(af, bf, acc);
    }
  }
#pragma unroll
  for (int q = 0; q < 4; ++q)
    t[(r0 + (l >> 4) * 4 + q) * 16 + (l & 15)] = acc[q];
}

// ---------------------------------------------------------------------------
// tail1: c1 (from t) + elu -> conv2 + elu + pool -> flat (global, f32)
// ---------------------------------------------------------------------------
__global__ __launch_bounds__(256) void tail1_kernel(
    const float* __restrict__ t, const float* __restrict__ bias_t,
    const float* __restrict__ b1, const float* __restrict__ w2,
    const float* __restrict__ b2, float* __restrict__ flat) {
  __shared__ float ts[512][16];
  __shared__ float c1s[5][512];
  int b = blockIdx.x, tid = threadIdx.x;
  const float4* tsrc = (const float4*)(t + (long)b * 8192);
  float4* tdst = (float4*)&ts[0][0];
#pragma unroll
  for (int i = 0; i < 8; ++i) tdst[tid + i * 256] = tsrc[tid + i * 256];
  __syncthreads();
#pragma unroll
  for (int i = 0; i < 10; ++i) {
    int idx = tid + i * 256;  // 0..2559
    int o = idx >> 9, s = idx & 511;
    float a = b1[o];
#pragma unroll
    for (int k = 0; k < 3; ++k) {
      int ss = s + k - 1;
      if (ss >= 0 && ss < 512) a += ts[ss][o * 3 + k] + bias_t[o * 3 + k];
    }
    c1s[o][s] = eluf(a);
  }
  __syncthreads();
#pragma unroll
  for (int i = 0; i < 2; ++i) {
    int r = tid + i * 256;  // 0..511
    int o = r >> 8, sp = r & 255;
    float mx = -1e30f;
#pragma unroll
    for (int sd = 0; sd < 2; ++sd) {
      int s = sp * 2 + sd;
      float a = b2[o];
#pragma unroll
      for (int ic = 0; ic < 5; ++ic)
#pragma unroll
        for (int k = 0; k < 3; ++k) {
          int ss = s + k - 1;
          if (ss >= 0 && ss < 512) a += c1s[ic][ss] * w2[(o * 5 + ic) * 3 + k];
        }
      mx = fmaxf(mx, eluf(a));
    }
    flat[(long)b * 512 + r] = mx;
  }
}

// ---------------------------------------------------------------------------
// head: fc1+fc2+fc3+LN; 1024 threads, split-K partials
// ---------------------------------------------------------------------------
__global__ __launch_bounds__(1024) void head_kernel(
    const float* __restrict__ flat, const float* __restrict__ fw1,
    const float* __restrict__ fb1, const float* __restrict__ fw2,
    const float* __restrict__ fb2, const float* __restrict__ fw3,
    const float* __restrict__ fb3, const float* __restrict__ g,
    const float* __restrict__ be, float* __restrict__ out) {
  __shared__ float xb[512];
  __shared__ float z1p[4][256];
  __shared__ float z1[256];
  __shared__ float z2p[2][128];
  __shared__ float z2[128];
  __shared__ float z3[96];
  int b = blockIdx.x, t = threadIdx.x;
  if (t < 512) xb[t] = flat[(long)b * 512 + t];
  __syncthreads();
  {
    int o = t & 255, part = t >> 8;
    float a = 0.f;
    const float* wp = fw1 + (long)part * 128 * 256 + o;
    const float* xp = xb + part * 128;
#pragma unroll 8
    for (int i = 0; i < 128; ++i) a += xp[i] * wp[i * 256];
    z1p[part][o] = a;
  }
  __syncthreads();
  if (t < 256)
    z1[t] = eluf(fb1[t] + z1p[0][t] + z1p[1][t] + z1p[2][t] + z1p[3][t]);
  __syncthreads();
  if (t < 256) {
    int o = t & 127, part = t >> 7;
    float a = 0.f;
    const float* wp = fw2 + (long)part * 128 * 128 + o;
    const float* xp = z1 + part * 128;
#pragma unroll 8
    for (int i = 0; i < 128; ++i) a += xp[i] * wp[i * 128];
    z2p[part][o] = a;
  }
  __syncthreads();
  if (t < 128) z2[t] = eluf(fb2[t] + z2p[0][t] + z2p[1][t]);
  __syncthreads();
  if (t < 96) {
    float a = fb3[t];
#pragma unroll 8
    for (int i = 0; i < 128; ++i) a += z2[i] * fw3[i * 96 + t];
    z3[t] = a;
  }
  __syncthreads();
  if (t < 96) {
    float mu = 0.f;
    for (int j = 0; j < 96; ++j) mu += z3[j];
    mu *= (1.f / 96.f);
    float sq = 0.f;
    for (int j = 0; j < 96; ++j) {
      float d = z3[j] - mu;
      sq += d * d;
    }
    float var = sq * (1.f / 96.f);
    out[b * 96 + t] = (z3[t] - mu) / sqrtf(var + 1e-5f) * g[t] + be[t];
  }
}

// ---------------------------------------------------------------------------
extern "C" void kernel_launch(void* const* d_in, const int* in_sizes, int n_in,
                              void* d_out, int out_size, void* d_ws,
                              size_t ws_size, hipStream_t stream) {
  (void)in_sizes; (void)n_in; (void)out_size;
  const float* x    = (const float*)d_in[0];
  const float* embW = (const float*)d_in[1];
  const float* embB = (const float*)d_in[2];
  const float* Wq   = (const float*)d_in[3];
  const float* bq   = (const float*)d_in[4];
  const float* Wk   = (const float*)d_in[5];
  const float* bk   = (const float*)d_in[6];
  const float* Wv   = (const float*)d_in[7];
  const float* bv   = (const float*)d_in[8];
  const float* Wo   = (const float*)d_in[9];
  const float* bo   = (const float*)d_in[10];
  const float* c1w  = (const float*)d_in[11];
  const float* c1b  = (const float*)d_in[12];
  const float* c2w  = (const float*)d_in[13];
  const float* c2b  = (const float*)d_in[14];
  const float* f1w  = (const float*)d_in[15];
  const float* f1b  = (const float*)d_in[16];
  const float* f2w  = (const float*)d_in[17];
  const float* f2b_ = (const float*)d_in[18];
  const float* f3w  = (const float*)d_in[19];
  const float* f3b  = (const float*)d_in[20];
  const float* lng  = (const float*)d_in[21];
  const float* lnb  = (const float*)d_in[22];
  float* out = (float*)d_out;

  char* p = (char*)d_ws;
  const size_t NEED = 182181952;
  if (ws_size < NEED) return;
  const long MS = 8388608;  // per-module stride in u16 elements (16 MB)

  u16*   A_pe    = (u16*)(p + 0);
  u16*   WTqkv   = (u16*)(p + 524288);
  float* pb_bias = (float*)(p + 6815744);
  float* EW      = (float*)(p + 6840320);
  u16*   PB      = (u16*)(p + 6938624);
  u16*   Q2      = (u16*)(p + 13230080);
  u16*   K2      = (u16*)(p + 46784512);
  u16*   VT2     = (u16*)(p + 80338944);
  u16*   ctx4    = (u16*)(p + 113893376);
  u16*   WEFFT   = (u16*)(p + 181002240);
  float* bias_t  = (float*)(p + 181067776);
  float* t_buf   = (float*)(p + 181067840);
  float* flat    = (float*)(p + 182116416);

  prep_misc<<<1061, 256, 0, stream>>>(embB, bq, bk, bv, Wq, Wk, Wv, embW, Wo,
                                      bo, c1w, A_pe, pb_bias, EW, WEFFT,
                                      bias_t);
  transw<<<dim3(12, 8, 8), 256, 0, stream>>>(Wq, Wk, Wv, WTqkv);
  gemm_bt<true><<<dim3(4, 4, 12), 256, 0, stream>>>(
      A_pe, 0, 512, WTqkv, pb_bias, (void*)PB, 262144, 512);

  for (int gp = 0; gp < 2; ++gp) {
    qkv_fused<<<dim3(256, 8, 2), 256, 0, stream>>>(x, EW, PB, Q2, K2, VT2,
                                                   gp * 2, MS);
    attn_kernel<<<dim3(256, 4, 2), 256, 0, stream>>>(
        Q2, K2, VT2, ctx4 + (long)gp * 2 * MS, MS);
  }

  t_gemm<<<1024, 64, 0, stream>>>(ctx4, WEFFT, t_buf);
  tail1_kernel<<<32, 256, 0, stream>>>(t_buf, bias_t, c1b, c2w, c2b, flat);
  head_kernel<<<32, 1024, 0, stream>>>(flat, f1w, f1b, f2w, f2b_, f3w, f3b,
                                       lng, lnb, out);
}

// Round 10
// 250.750 us; speedup vs baseline: 1.6267x; 1.0651x over previous
//
#include <hip/hip_runtime.h>
#include <math.h>

typedef unsigned short u16;
typedef unsigned int u32;
typedef __attribute__((ext_vector_type(8))) short short8;
typedef __attribute__((ext_vector_type(4))) float f32x4;
typedef __attribute__((ext_vector_type(16))) float f32x16;
typedef __attribute__((ext_vector_type(4))) u32 u32x4;
typedef __attribute__((ext_vector_type(2))) u32 u32x2;

__device__ inline u16 f2b(float f) {
  u32 u = __builtin_bit_cast(u32, f);
  u32 r = u + 0x7fffu + ((u >> 16) & 1u);
  return (u16)(r >> 16);
}
__device__ inline float b2f(u16 b) {
  return __builtin_bit_cast(float, (u32)b << 16);
}
// HW packed f32->bf16 (RTNE), 1 instruction for 2 values
__device__ inline u32 cvtpk(float lo, float hi) {
  u32 r;
  asm("v_cvt_pk_bf16_f32 %0, %1, %2" : "=v"(r) : "v"(lo), "v"(hi));
  return r;
}
__device__ inline float eluf(float x) { return x > 0.f ? x : expf(x) - 1.f; }

__device__ inline f32x4 mfma16(short8 a, short8 b, f32x4 c) {
  return __builtin_amdgcn_mfma_f32_16x16x32_bf16(a, b, c, 0, 0, 0);
}
__device__ inline f32x16 mfma32(short8 a, short8 b, f32x16 c) {
  return __builtin_amdgcn_mfma_f32_32x32x16_bf16(a, b, c, 0, 0, 0);
}
__device__ inline void gload16(const u16* g, u16* l) {
  __builtin_amdgcn_global_load_lds((__attribute__((address_space(1))) void*)(g),
                                   (__attribute__((address_space(3))) void*)(l),
                                   16, 0, 0);
}

// ---------------------------------------------------------------------------
// prep_misc: fused prep_pe + pb_bias gather + EW + WEFF/bias_t
// ---------------------------------------------------------------------------
__global__ __launch_bounds__(256) void prep_misc(
    const float* __restrict__ emb_b, const float* __restrict__ bq,
    const float* __restrict__ bk, const float* __restrict__ bv,
    const float* __restrict__ Wq, const float* __restrict__ Wk,
    const float* __restrict__ Wv, const float* __restrict__ embW,
    const float* __restrict__ Wo, const float* __restrict__ bo,
    const float* __restrict__ w1, u16* __restrict__ A_pe,
    float* __restrict__ pb_bias, float* __restrict__ EW,
    u16* __restrict__ WEFFT, float* __restrict__ bias_t) {
  __shared__ float smem[2048];
  const int bid = blockIdx.x, t = threadIdx.x;
  if (bid < 512) {
    int s = bid;
    float div = expf((2.f * t) * (-9.210340371976184f / 512.f));
    float arg = (float)s * div;
    A_pe[s * 512 + 2 * t] = f2b(sinf(arg) + emb_b[2 * t]);
    A_pe[s * 512 + 2 * t + 1] = f2b(cosf(arg) + emb_b[2 * t + 1]);
  } else if (bid < 536) {
    int i = (bid - 512) * 256 + t;  // 0..6143
    int z = i >> 9, e = i & 511;
    int ty = z >> 2, m = z & 3;
    const float* bp = (ty == 0) ? bq : (ty == 1) ? bk : bv;
    pb_bias[i] = bp[m * 512 + e];
  } else if (bid < 548) {
    int z = bid - 536;
    const float* W =
        ((z < 4) ? Wq : (z < 8) ? Wk : Wv) + (long)(z & 3) * 262144;
#pragma unroll
    for (int i = 0; i < 8; ++i) smem[t + i * 256] = embW[t + i * 256];
    __syncthreads();
    float a[4][2] = {};
    for (int d = 0; d < 512; ++d) {
      float w0 = W[(long)d * 512 + t];
      float w1v = W[(long)d * 512 + t + 256];
#pragma unroll
      for (int f = 0; f < 4; ++f) {
        float e = smem[f * 512 + d];
        a[f][0] += e * w0;
        a[f][1] += e * w1v;
      }
    }
#pragma unroll
    for (int f = 0; f < 4; ++f) {
      EW[((long)z * 4 + f) * 512 + t] = a[f][0];
      EW[((long)z * 4 + f) * 512 + t + 256] = a[f][1];
    }
  } else {
    const int wb = bid - 548;  // 0..512
    const int w = t >> 6, l = t & 63;
    if (wb < 512) {
      int idx = wb * 4 + w;  // 0..2047
      int m = idx >> 9, d = idx & 511;
      const float* wrow = Wo + ((long)m * 512 + d) * 512;
      float a[15] = {};
#pragma unroll
      for (int i = 0; i < 8; ++i) {
        int e = l * 8 + i;
        float wv = wrow[e];
#pragma unroll
        for (int o = 0; o < 5; ++o)
#pragma unroll
          for (int k = 0; k < 3; ++k)
            a[o * 3 + k] += wv * w1[((long)o * 2048 + m * 512 + e) * 3 + k];
      }
#pragma unroll
      for (int j = 0; j < 15; ++j) {
        float v = a[j];
        for (int o = 1; o < 64; o <<= 1) v += __shfl_xor(v, o);
        if (l == 0) WEFFT[((long)m * 16 + j) * 512 + d] = f2b(v);
      }
      if (l == 0) WEFFT[((long)m * 16 + 15) * 512 + d] = 0;
    } else if (w == 0) {
      float a[15] = {};
      for (int c = l; c < 2048; c += 64) {
        float bv = bo[c];
#pragma unroll
        for (int o = 0; o < 5; ++o)
#pragma unroll
          for (int k = 0; k < 3; ++k)
            a[o * 3 + k] += bv * w1[((long)o * 2048 + c) * 3 + k];
      }
#pragma unroll
      for (int j = 0; j < 15; ++j) {
        float v = a[j];
        for (int o = 1; o < 64; o <<= 1) v += __shfl_xor(v, o);
        if (l == 0) bias_t[j] = v;
      }
      if (l == 0) bias_t[15] = 0.f;
    }
  }
}

// ---------------------------------------------------------------------------
// transpose the 12 QKV weight matrices -> bf16 [e][d]
// ---------------------------------------------------------------------------
__global__ __launch_bounds__(256) void transw(
    const float* __restrict__ Wq, const float* __restrict__ Wk,
    const float* __restrict__ Wv, u16* __restrict__ WTqkv) {
  __shared__ float tile[64][65];
  int mid = blockIdx.x;
  const float* W = ((mid < 4) ? Wq : (mid < 8) ? Wk : Wv) + (long)(mid & 3) * 262144;
  u16* WT = WTqkv + (long)mid * 262144;
  int d0 = blockIdx.y * 64, e0 = blockIdx.z * 64;
  int t = threadIdx.x;
  int dr = t >> 2, ec = (t & 3) * 16;
#pragma unroll
  for (int j = 0; j < 16; j += 4) {
    float4 v = *(const float4*)&W[(long)(d0 + dr) * 512 + e0 + ec + j];
    tile[dr][ec + j] = v.x;
    tile[dr][ec + j + 1] = v.y;
    tile[dr][ec + j + 2] = v.z;
    tile[dr][ec + j + 3] = v.w;
  }
  __syncthreads();
  int er = t >> 2, dc = (t & 3) * 16;
  u16 tmp[16] __attribute__((aligned(16)));
#pragma unroll
  for (int j = 0; j < 16; ++j) tmp[j] = f2b(tile[dc + j][er]);
  *(short8*)&WT[(long)(e0 + er) * 512 + d0 + dc] = *(short8*)&tmp[0];
  *(short8*)&WT[(long)(e0 + er) * 512 + d0 + dc + 8] = *(short8*)&tmp[8];
}

// ---------------------------------------------------------------------------
// generic bf16 GEMM  C[r][c] = sum_k A[r][k] * BT[c][k] + bias[c]
// ---------------------------------------------------------------------------
template <bool OBF>
__global__ __launch_bounds__(256) void gemm_bt(
    const u16* __restrict__ A, long sAz, int lda, const u16* __restrict__ BT,
    const float* __restrict__ bias, void* __restrict__ out, long sOz, int ldo) {
  __shared__ u16 As[128 * 32];
  __shared__ u16 Bs[128 * 32];
  const int z = blockIdx.z;
  const int tid = threadIdx.x, w = tid >> 6, l = tid & 63;
  const long row0 = (long)blockIdx.y * 128;
  const u16* Ab = A + (long)z * sAz + row0 * lda;
  const u16* Bb = BT + (long)z * 262144 + (long)blockIdx.x * 128 * 512;
  const u16* ga = Ab + (long)(w * 32 + (l >> 2)) * lda + (l & 3) * 8;
  const u16* gb = Bb + (long)(w * 32 + (l >> 2)) * 512 + (l & 3) * 8;
  u16* lA = As + w * 32 * 32;
  u16* lB = Bs + w * 32 * 32;
  f32x4 acc[4][4] = {};
  const int wr = (w >> 1) * 64, wc = (w & 1) * 64;
  for (int kt = 0; kt < 16; ++kt) {
    gload16(ga + kt * 32, lA);
    gload16(ga + kt * 32 + 16 * lda, lA + 16 * 32);
    gload16(gb + kt * 32, lB);
    gload16(gb + kt * 32 + 16 * 512, lB + 16 * 32);
    __syncthreads();
    short8 af[4], bf[4];
#pragma unroll
    for (int i = 0; i < 4; ++i)
      af[i] = *(const short8*)&As[(wr + i * 16 + (l & 15)) * 32 + (l >> 4) * 8];
#pragma unroll
    for (int i = 0; i < 4; ++i)
      bf[i] = *(const short8*)&Bs[(wc + i * 16 + (l & 15)) * 32 + (l >> 4) * 8];
#pragma unroll
    for (int i = 0; i < 4; ++i)
#pragma unroll
      for (int j = 0; j < 4; ++j) acc[i][j] = mfma16(af[i], bf[j], acc[i][j]);
    __syncthreads();
  }
  const int colB = blockIdx.x * 128 + wc;
#pragma unroll
  for (int i = 0; i < 4; ++i)
#pragma unroll
    for (int j = 0; j < 4; ++j) {
      int col = colB + j * 16 + (l & 15);
      float bb = bias[(long)z * 512 + col];
#pragma unroll
      for (int q = 0; q < 4; ++q) {
        long r = row0 + wr + i * 16 + (l >> 4) * 4 + q;
        float v = acc[i][j][q] + bb;
        if (OBF)
          ((u16*)out)[(long)z * sOz + r * ldo + col] = f2b(v);
        else
          ((float*)out)[(long)z * sOz + r * ldo + col] = v;
      }
    }
}

// ---------------------------------------------------------------------------
// fused QKV + V-transpose. block = (b*8+h, s-tile of 64, module m=z).
// ---------------------------------------------------------------------------
__global__ __launch_bounds__(256) void qkv_fused(
    const float* __restrict__ x, const float* __restrict__ EW,
    const u16* __restrict__ PB, u16* __restrict__ Q, u16* __restrict__ K,
    u16* __restrict__ VT, long mstride) {
  __shared__ float ews[3][4][64];
  __shared__ u16 vtile[64][72];
  const int bh = blockIdx.x;  // b*8+h
  const int st = blockIdx.y;
  const int m = blockIdx.z;
  const int b = bh >> 3, h = bh & 7;
  const int hoff = h * 64;
  const int t = threadIdx.x;
  if (t < 192) {
    int ty = t >> 6, dk = t & 63;
#pragma unroll
    for (int f = 0; f < 4; ++f)
      ews[ty][f][dk] = EW[(((long)(ty * 4 + m)) * 4 + f) * 512 + hoff + dk];
  }
  __syncthreads();
  const int sr = t >> 2, cq = t & 3;
  const int s = st * 64 + sr;
  const long rid = (long)b * 512 + s;
  const float* xr = x + rid * 7;
  const float xd = xr[3 + m], x0 = xr[0], x1 = xr[1], x2 = xr[2];
  const long obase = (long)m * mstride + rid * 512 + hoff + cq * 16;

  float res[3][16];
#pragma unroll
  for (int ty = 0; ty < 3; ++ty) {
    const u16* pbp =
        PB + (((long)(ty * 4 + m)) * 512 + s) * 512 + hoff + cq * 16;
    short8 pbv0 = *(const short8*)pbp;
    short8 pbv1 = *(const short8*)(pbp + 8);
#pragma unroll
    for (int j = 0; j < 16; ++j) {
      int dk = cq * 16 + j;
      u16 pb = (u16)(j < 8 ? pbv0[j] : pbv1[j - 8]);
      res[ty][j] = xd * ews[ty][0][dk] + x0 * ews[ty][1][dk] +
                   x1 * ews[ty][2][dk] + x2 * ews[ty][3][dk] + b2f(pb);
    }
  }
#pragma unroll
  for (int ty = 0; ty < 2; ++ty) {
    float ss = 0.f;
#pragma unroll
    for (int j = 0; j < 16; ++j) ss += res[ty][j] * res[ty][j];
    ss += __shfl_xor(ss, 1);
    ss += __shfl_xor(ss, 2);
    float sc = 1.f / fmaxf(sqrtf(ss), 1e-12f);
    u32 o[8];
#pragma unroll
    for (int jj = 0; jj < 8; ++jj)
      o[jj] = cvtpk(res[ty][2 * jj] * sc, res[ty][2 * jj + 1] * sc);
    u16* P = ty ? K : Q;
    *(u32x4*)&P[obase] = *(u32x4*)&o[0];
    *(u32x4*)&P[obase + 8] = *(u32x4*)&o[4];
  }
  {
    u32 o[8];
#pragma unroll
    for (int jj = 0; jj < 8; ++jj)
      o[jj] = cvtpk(res[2][2 * jj], res[2][2 * jj + 1]);
    *(short8*)&vtile[sr][cq * 16] = *(short8*)&o[0];
    *(short8*)&vtile[sr][cq * 16 + 8] = *(short8*)&o[4];
  }
  __syncthreads();
  {
    int kr = t >> 2, sc2 = (t & 3) * 16;
    u16 tmp[16] __attribute__((aligned(16)));
#pragma unroll
    for (int j = 0; j < 16; ++j) tmp[j] = vtile[sc2 + j][kr];
    long gdst = (long)m * mstride + ((long)bh * 64 + kr) * 512 + st * 64 + sc2;
    *(short8*)&VT[gdst] = *(short8*)&tmp[0];
    *(short8*)&VT[gdst + 8] = *(short8*)&tmp[8];
  }
}

// ---------------------------------------------------------------------------
// flash attention, max-free, 32x32 swapped-operand; 8-wave blocks (512 thr)
// covering 256 q-rows; counted vmcnt(2); P = __expf(S) (f32 log2e mul stays
// in-register — folding it into bf16 K costs too much precision, round 9).
// ctx aliases Q (block-private region).
// ---------------------------------------------------------------------------
__global__ __launch_bounds__(512, 4) void attn_kernel(
    const u16* Qg, const u16* __restrict__ Kg, const u16* __restrict__ VTg,
    u16* ctxg, long mstride) {
  __shared__ u16 Kb[2][64][64];
  __shared__ u16 Vb[2][64][64];
  const u16* Q = Qg + (long)blockIdx.z * mstride;
  const u16* K = Kg + (long)blockIdx.z * mstride;
  const u16* VT = VTg + (long)blockIdx.z * mstride;
  u16* ctx = ctxg + (long)blockIdx.z * mstride;
  const int bh = blockIdx.x;  // b*8+h
  const int qp = blockIdx.y;  // 0..1, 256 q-rows each
  const int b = bh >> 3, h = bh & 7;
  const int tid = threadIdx.x, w = tid >> 6, l = tid & 63;
  const int lq = l & 31, hi = l >> 5, l7 = l & 7;
  const long rowbase = (long)b * 512;
  const int hoff = h * 64;
  const int rw = l >> 3, gch = (l & 7) ^ rw;
  const int qrow = qp * 256 + w * 32;

  short8 qf[4];
  {
    const u16* qrp = Q + (rowbase + qrow + lq) * 512 + hoff + hi * 8;
#pragma unroll
    for (int dc = 0; dc < 4; ++dc) qf[dc] = *(const short8*)(qrp + dc * 16);
  }

  short8 ones;
#pragma unroll
  for (int i = 0; i < 8; ++i) ones[i] = (short)0x3F80;  // bf16 1.0

  f32x16 o_acc[2] = {};
  f32x16 l_acc = {};

  const u16* Kgbase = K + rowbase * 512 + hoff + gch * 8;
  const u16* Vgbase = VT + (long)bh * 64 * 512 + gch * 8;

  // 8 waves: wave w stages rows w*8..w*8+7 of the 64-row tile (2 loads/wave)
#define STAGE(bf, kt)                                                         \
  {                                                                           \
    int rr = w * 8;                                                           \
    gload16(Kgbase + (long)((kt)*64 + rr + rw) * 512, &Kb[bf][rr][0]);        \
    gload16(Vgbase + (long)(rr + rw) * 512 + (kt)*64, &Vb[bf][rr][0]);        \
  }

  STAGE(0, 0);  // 2 loads in flight

  for (int kt = 0; kt < 8; ++kt) {
    const int cur = kt & 1;
    if (kt < 7) {
      STAGE(cur ^ 1, kt + 1);  // issue next tile (2 more loads)
      asm volatile("s_waitcnt vmcnt(2)" ::: "memory");  // tile kt ready
    } else {
      asm volatile("s_waitcnt vmcnt(0)" ::: "memory");
    }
    __builtin_amdgcn_s_barrier();  // all waves' tile kt in LDS
    __builtin_amdgcn_sched_barrier(0);
    __builtin_amdgcn_s_setprio(1);
#pragma unroll
    for (int ktile = 0; ktile < 2; ++ktile) {
      f32x16 s = {};
#pragma unroll
      for (int dc = 0; dc < 4; ++dc) {
        short8 kf = *(const short8*)((const char*)&Kb[cur][ktile * 32 + lq][0] +
                                     (((dc * 2 + hi) ^ l7) * 16));
        s = mfma32(kf, qf[dc], s);
      }
      float p[16];
#pragma unroll
      for (int r = 0; r < 16; ++r) p[r] = __expf(s[r]);
      u32 A0 = cvtpk(p[0], p[1]), A1 = cvtpk(p[2], p[3]);
      u32 A2 = cvtpk(p[4], p[5]), A3 = cvtpk(p[6], p[7]);
      u32 A4 = cvtpk(p[8], p[9]), A5 = cvtpk(p[10], p[11]);
      u32 A6 = cvtpk(p[12], p[13]), A7 = cvtpk(p[14], p[15]);
      u32 pA0 = __shfl_xor(A0, 32), pA1 = __shfl_xor(A1, 32);
      u32 pA2 = __shfl_xor(A2, 32), pA3 = __shfl_xor(A3, 32);
      u32 pA4 = __shfl_xor(A4, 32), pA5 = __shfl_xor(A5, 32);
      u32 pA6 = __shfl_xor(A6, 32), pA7 = __shfl_xor(A7, 32);
      u32x4 f0 = {hi ? pA2 : A0, hi ? pA3 : A1, hi ? A2 : pA0, hi ? A3 : pA1};
      u32x4 f1 = {hi ? pA6 : A4, hi ? pA7 : A5, hi ? A6 : pA4, hi ? A7 : pA5};
      short8 bf0 = __builtin_bit_cast(short8, f0);
      short8 bf1 = __builtin_bit_cast(short8, f1);
#pragma unroll
      for (int kk2 = 0; kk2 < 2; ++kk2) {
        const int kc = ktile * 2 + kk2;
        short8 pb = kk2 ? bf1 : bf0;
        l_acc = mfma32(ones, pb, l_acc);  // row-sum on matrix pipe
#pragma unroll
        for (int dt = 0; dt < 2; ++dt) {
          short8 vf =
              *(const short8*)((const char*)&Vb[cur][dt * 32 + lq][0] +
                               (((kc * 2 + hi) ^ l7) * 16));
          o_acc[dt] = mfma32(vf, pb, o_acc[dt]);
        }
      }
    }
    __builtin_amdgcn_s_setprio(0);
    __builtin_amdgcn_sched_barrier(0);
    __builtin_amdgcn_s_barrier();  // all waves done reading cur (no drain)
    __builtin_amdgcn_sched_barrier(0);
  }
#undef STAGE
  const float inv = 1.f / l_acc[0];
  u16* crow = ctx + (rowbase + qrow + lq) * 512 + hoff + hi * 4;
#pragma unroll
  for (int dt = 0; dt < 2; ++dt)
#pragma unroll
    for (int rq = 0; rq < 4; ++rq) {
      u32 w0 = cvtpk(o_acc[dt][rq * 4 + 0] * inv, o_acc[dt][rq * 4 + 1] * inv);
      u32 w1 = cvtpk(o_acc[dt][rq * 4 + 2] * inv, o_acc[dt][rq * 4 + 3] * inv);
      u32x2 pr = {w0, w1};
      *(u32x2*)&crow[dt * 32 + rq * 8] = pr;
    }
}

// ---------------------------------------------------------------------------
// t[r][j] = sum_m ctx_m[r][:] . WEFFT[m][j][:]
// ---------------------------------------------------------------------------
__global__ __launch_bounds__(64) void t_gemm(const u16* __restrict__ ctx4,
                                             const u16* __restrict__ WEFFT,
                                             float* __restrict__ t) {
  const int l = threadIdx.x;
  const long r0 = (long)blockIdx.x * 16;
  f32x4 acc = {};
#pragma unroll
  for (int m = 0; m < 4; ++m) {
    const u16* A =
        ctx4 + (long)m * 8388608 + (r0 + (l & 15)) * 512 + (l >> 4) * 8;
    const u16* Bb = WEFFT + m * 8192 + (l & 15) * 512 + (l >> 4) * 8;
#pragma unroll
    for (int kt = 0; kt < 16; ++kt) {
      short8 af = *(const short8*)(A + kt * 32);
      short8 bf = *(const short8*)(Bb + kt * 32);
      acc = mfma16(af, bf, acc);
    }
  }
#pragma unroll
  for (int q = 0; q < 4; ++q)
    t[(r0 + (l >> 4) * 4 + q) * 16 + (l & 15)] = acc[q];
}

// ---------------------------------------------------------------------------
// tail1: c1 (from t) + elu -> conv2 + elu + pool -> flat (global, f32)
// ---------------------------------------------------------------------------
__global__ __launch_bounds__(256) void tail1_kernel(
    const float* __restrict__ t, const float* __restrict__ bias_t,
    const float* __restrict__ b1, const float* __restrict__ w2,
    const float* __restrict__ b2, float* __restrict__ flat) {
  __shared__ float ts[512][16];
  __shared__ float c1s[5][512];
  int b = blockIdx.x, tid = threadIdx.x;
  const float4* tsrc = (const float4*)(t + (long)b * 8192);
  float4* tdst = (float4*)&ts[0][0];
#pragma unroll
  for (int i = 0; i < 8; ++i) tdst[tid + i * 256] = tsrc[tid + i * 256];
  __syncthreads();
#pragma unroll
  for (int i = 0; i < 10; ++i) {
    int idx = tid + i * 256;  // 0..2559
    int o = idx >> 9, s = idx & 511;
    float a = b1[o];
#pragma unroll
    for (int k = 0; k < 3; ++k) {
      int ss = s + k - 1;
      if (ss >= 0 && ss < 512) a += ts[ss][o * 3 + k] + bias_t[o * 3 + k];
    }
    c1s[o][s] = eluf(a);
  }
  __syncthreads();
#pragma unroll
  for (int i = 0; i < 2; ++i) {
    int r = tid + i * 256;  // 0..511
    int o = r >> 8, sp = r & 255;
    float mx = -1e30f;
#pragma unroll
    for (int sd = 0; sd < 2; ++sd) {
      int s = sp * 2 + sd;
      float a = b2[o];
#pragma unroll
      for (int ic = 0; ic < 5; ++ic)
#pragma unroll
        for (int k = 0; k < 3; ++k) {
          int ss = s + k - 1;
          if (ss >= 0 && ss < 512) a += c1s[ic][ss] * w2[(o * 5 + ic) * 3 + k];
        }
      mx = fmaxf(mx, eluf(a));
    }
    flat[(long)b * 512 + r] = mx;
  }
}

// ---------------------------------------------------------------------------
// head: fc1+fc2+fc3+LN; 1024 threads, split-K partials
// ---------------------------------------------------------------------------
__global__ __launch_bounds__(1024) void head_kernel(
    const float* __restrict__ flat, const float* __restrict__ fw1,
    const float* __restrict__ fb1, const float* __restrict__ fw2,
    const float* __restrict__ fb2, const float* __restrict__ fw3,
    const float* __restrict__ fb3, const float* __restrict__ g,
    const float* __restrict__ be, float* __restrict__ out) {
  __shared__ float xb[512];
  __shared__ float z1p[4][256];
  __shared__ float z1[256];
  __shared__ float z2p[2][128];
  __shared__ float z2[128];
  __shared__ float z3[96];
  int b = blockIdx.x, t = threadIdx.x;
  if (t < 512) xb[t] = flat[(long)b * 512 + t];
  __syncthreads();
  {
    int o = t & 255, part = t >> 8;
    float a = 0.f;
    const float* wp = fw1 + (long)part * 128 * 256 + o;
    const float* xp = xb + part * 128;
#pragma unroll 8
    for (int i = 0; i < 128; ++i) a += xp[i] * wp[i * 256];
    z1p[part][o] = a;
  }
  __syncthreads();
  if (t < 256)
    z1[t] = eluf(fb1[t] + z1p[0][t] + z1p[1][t] + z1p[2][t] + z1p[3][t]);
  __syncthreads();
  if (t < 256) {
    int o = t & 127, part = t >> 7;
    float a = 0.f;
    const float* wp = fw2 + (long)part * 128 * 128 + o;
    const float* xp = z1 + part * 128;
#pragma unroll 8
    for (int i = 0; i < 128; ++i) a += xp[i] * wp[i * 128];
    z2p[part][o] = a;
  }
  __syncthreads();
  if (t < 128) z2[t] = eluf(fb2[t] + z2p[0][t] + z2p[1][t]);
  __syncthreads();
  if (t < 96) {
    float a = fb3[t];
#pragma unroll 8
    for (int i = 0; i < 128; ++i) a += z2[i] * fw3[i * 96 + t];
    z3[t] = a;
  }
  __syncthreads();
  if (t < 96) {
    float mu = 0.f;
    for (int j = 0; j < 96; ++j) mu += z3[j];
    mu *= (1.f / 96.f);
    float sq = 0.f;
    for (int j = 0; j < 96; ++j) {
      float d = z3[j] - mu;
      sq += d * d;
    }
    float var = sq * (1.f / 96.f);
    out[b * 96 + t] = (z3[t] - mu) / sqrtf(var + 1e-5f) * g[t] + be[t];
  }
}

// ---------------------------------------------------------------------------
extern "C" void kernel_launch(void* const* d_in, const int* in_sizes, int n_in,
                              void* d_out, int out_size, void* d_ws,
                              size_t ws_size, hipStream_t stream) {
  (void)in_sizes; (void)n_in; (void)out_size;
  const float* x    = (const float*)d_in[0];
  const float* embW = (const float*)d_in[1];
  const float* embB = (const float*)d_in[2];
  const float* Wq   = (const float*)d_in[3];
  const float* bq   = (const float*)d_in[4];
  const float* Wk   = (const float*)d_in[5];
  const float* bk   = (const float*)d_in[6];
  const float* Wv   = (const float*)d_in[7];
  const float* bv   = (const float*)d_in[8];
  const float* Wo   = (const float*)d_in[9];
  const float* bo   = (const float*)d_in[10];
  const float* c1w  = (const float*)d_in[11];
  const float* c1b  = (const float*)d_in[12];
  const float* c2w  = (const float*)d_in[13];
  const float* c2b  = (const float*)d_in[14];
  const float* f1w  = (const float*)d_in[15];
  const float* f1b  = (const float*)d_in[16];
  const float* f2w  = (const float*)d_in[17];
  const float* f2b_ = (const float*)d_in[18];
  const float* f3w  = (const float*)d_in[19];
  const float* f3b  = (const float*)d_in[20];
  const float* lng  = (const float*)d_in[21];
  const float* lnb  = (const float*)d_in[22];
  float* out = (float*)d_out;

  char* p = (char*)d_ws;
  const size_t NEED = 215736384;
  if (ws_size < NEED) return;
  const long MS = 8388608;  // per-module stride in u16 elements (16 MB)

  u16*   A_pe    = (u16*)(p + 0);
  u16*   WTqkv   = (u16*)(p + 524288);
  float* pb_bias = (float*)(p + 6815744);
  float* EW      = (float*)(p + 6840320);
  u16*   PB      = (u16*)(p + 6938624);
  u16*   Q4      = (u16*)(p + 13230080);   // 4 x 16.77 MB ; ctx4 aliases this
  u16*   K4      = (u16*)(p + 80338944);
  u16*   VT4     = (u16*)(p + 147447808);
  u16*   ctx4    = Q4;                     // attn writes ctx over its own Q
  u16*   WEFFT   = (u16*)(p + 214556672);
  float* bias_t  = (float*)(p + 214622208);
  float* t_buf   = (float*)(p + 214622272);
  float* flat    = (float*)(p + 215670848);

  prep_misc<<<1061, 256, 0, stream>>>(embB, bq, bk, bv, Wq, Wk, Wv, embW, Wo,
                                      bo, c1w, A_pe, pb_bias, EW, WEFFT,
                                      bias_t);
  transw<<<dim3(12, 8, 8), 256, 0, stream>>>(Wq, Wk, Wv, WTqkv);
  gemm_bt<true><<<dim3(4, 4, 12), 256, 0, stream>>>(
      A_pe, 0, 512, WTqkv, pb_bias, (void*)PB, 262144, 512);

  qkv_fused<<<dim3(256, 8, 4), 256, 0, stream>>>(x, EW, PB, Q4, K4, VT4, MS);
  attn_kernel<<<dim3(256, 2, 4), 512, 0, stream>>>(Q4, K4, VT4, ctx4, MS);

  t_gemm<<<1024, 64, 0, stream>>>(ctx4, WEFFT, t_buf);
  tail1_kernel<<<32, 256, 0, stream>>>(t_buf, bias_t, c1b, c2w, c2b, flat);
  head_kernel<<<32, 1024, 0, stream>>>(flat, f1w, f1b, f2w, f2b_, f3w, f3b,
                                       lng, lnb, out);
}

// Round 11
// 245.914 us; speedup vs baseline: 1.6586x; 1.0197x over previous
//
#include <hip/hip_runtime.h>
#include <math.h>

typedef unsigned short u16;
typedef unsigned int u32;
typedef __attribute__((ext_vector_type(8))) short short8;
typedef __attribute__((ext_vector_type(4))) float f32x4;
typedef __attribute__((ext_vector_type(16))) float f32x16;
typedef __attribute__((ext_vector_type(4))) u32 u32x4;
typedef __attribute__((ext_vector_type(2))) u32 u32x2;

__device__ inline u16 f2b(float f) {
  u32 u = __builtin_bit_cast(u32, f);
  u32 r = u + 0x7fffu + ((u >> 16) & 1u);
  return (u16)(r >> 16);
}
__device__ inline float b2f(u16 b) {
  return __builtin_bit_cast(float, (u32)b << 16);
}
// HW packed f32->bf16 (RTNE), 1 instruction for 2 values
__device__ inline u32 cvtpk(float lo, float hi) {
  u32 r;
  asm("v_cvt_pk_bf16_f32 %0, %1, %2" : "=v"(r) : "v"(lo), "v"(hi));
  return r;
}
__device__ inline float eluf(float x) { return x > 0.f ? x : expf(x) - 1.f; }

__device__ inline f32x4 mfma16(short8 a, short8 b, f32x4 c) {
  return __builtin_amdgcn_mfma_f32_16x16x32_bf16(a, b, c, 0, 0, 0);
}
__device__ inline f32x16 mfma32(short8 a, short8 b, f32x16 c) {
  return __builtin_amdgcn_mfma_f32_32x32x16_bf16(a, b, c, 0, 0, 0);
}
__device__ inline void gload16(const u16* g, u16* l) {
  __builtin_amdgcn_global_load_lds((__attribute__((address_space(1))) void*)(g),
                                   (__attribute__((address_space(3))) void*)(l),
                                   16, 0, 0);
}

// ---------------------------------------------------------------------------
// prep_misc: prep_pe + pb_bias + EW + WEFF/bias_t + transw (all one launch)
//   bid [0,512):      A_pe rows (PE + emb_b, bf16)
//   bid [512,536):    pb_bias gather
//   bid [536,548):    EW (z = bid-536)
//   bid [548,1061):   WEFF ; block 1060 wave0 = bias_t
//   bid [1061,1829):  transw 64x64 tiles (12 matrices x 64 tiles)
// ---------------------------------------------------------------------------
__global__ __launch_bounds__(256) void prep_misc(
    const float* __restrict__ emb_b, const float* __restrict__ bq,
    const float* __restrict__ bk, const float* __restrict__ bv,
    const float* __restrict__ Wq, const float* __restrict__ Wk,
    const float* __restrict__ Wv, const float* __restrict__ embW,
    const float* __restrict__ Wo, const float* __restrict__ bo,
    const float* __restrict__ w1, u16* __restrict__ A_pe,
    float* __restrict__ pb_bias, float* __restrict__ EW,
    u16* __restrict__ WEFFT, float* __restrict__ bias_t,
    u16* __restrict__ WTqkv) {
  __shared__ float smem[64 * 65];
  const int bid = blockIdx.x, t = threadIdx.x;
  if (bid < 512) {
    int s = bid;
    float div = expf((2.f * t) * (-9.210340371976184f / 512.f));
    float arg = (float)s * div;
    A_pe[s * 512 + 2 * t] = f2b(sinf(arg) + emb_b[2 * t]);
    A_pe[s * 512 + 2 * t + 1] = f2b(cosf(arg) + emb_b[2 * t + 1]);
  } else if (bid < 536) {
    int i = (bid - 512) * 256 + t;  // 0..6143
    int z = i >> 9, e = i & 511;
    int ty = z >> 2, m = z & 3;
    const float* bp = (ty == 0) ? bq : (ty == 1) ? bk : bv;
    pb_bias[i] = bp[m * 512 + e];
  } else if (bid < 548) {
    int z = bid - 536;
    const float* W =
        ((z < 4) ? Wq : (z < 8) ? Wk : Wv) + (long)(z & 3) * 262144;
#pragma unroll
    for (int i = 0; i < 8; ++i) smem[t + i * 256] = embW[t + i * 256];
    __syncthreads();
    float a[4][2] = {};
    for (int d = 0; d < 512; ++d) {
      float w0 = W[(long)d * 512 + t];
      float w1v = W[(long)d * 512 + t + 256];
#pragma unroll
      for (int f = 0; f < 4; ++f) {
        float e = smem[f * 512 + d];
        a[f][0] += e * w0;
        a[f][1] += e * w1v;
      }
    }
#pragma unroll
    for (int f = 0; f < 4; ++f) {
      EW[((long)z * 4 + f) * 512 + t] = a[f][0];
      EW[((long)z * 4 + f) * 512 + t + 256] = a[f][1];
    }
  } else if (bid < 1061) {
    const int wb = bid - 548;  // 0..512
    const int w = t >> 6, l = t & 63;
    if (wb < 512) {
      int idx = wb * 4 + w;  // 0..2047
      int m = idx >> 9, d = idx & 511;
      const float* wrow = Wo + ((long)m * 512 + d) * 512;
      float a[15] = {};
#pragma unroll
      for (int i = 0; i < 8; ++i) {
        int e = l * 8 + i;
        float wv = wrow[e];
#pragma unroll
        for (int o = 0; o < 5; ++o)
#pragma unroll
          for (int k = 0; k < 3; ++k)
            a[o * 3 + k] += wv * w1[((long)o * 2048 + m * 512 + e) * 3 + k];
      }
#pragma unroll
      for (int j = 0; j < 15; ++j) {
        float v = a[j];
        for (int o = 1; o < 64; o <<= 1) v += __shfl_xor(v, o);
        if (l == 0) WEFFT[((long)m * 16 + j) * 512 + d] = f2b(v);
      }
      if (l == 0) WEFFT[((long)m * 16 + 15) * 512 + d] = 0;
    } else if (w == 0) {
      float a[15] = {};
      for (int c = l; c < 2048; c += 64) {
        float bv = bo[c];
#pragma unroll
        for (int o = 0; o < 5; ++o)
#pragma unroll
          for (int k = 0; k < 3; ++k)
            a[o * 3 + k] += bv * w1[((long)o * 2048 + c) * 3 + k];
      }
#pragma unroll
      for (int j = 0; j < 15; ++j) {
        float v = a[j];
        for (int o = 1; o < 64; o <<= 1) v += __shfl_xor(v, o);
        if (l == 0) bias_t[j] = v;
      }
      if (l == 0) bias_t[15] = 0.f;
    }
  } else {
    // transw: bf16-transpose one 64x64 tile of one QKV weight matrix
    int bidt = bid - 1061;  // 0..767
    int mid = bidt >> 6, rest = bidt & 63;
    int d0 = (rest >> 3) * 64, e0 = (rest & 7) * 64;
    const float* W =
        ((mid < 4) ? Wq : (mid < 8) ? Wk : Wv) + (long)(mid & 3) * 262144;
    u16* WT = WTqkv + (long)mid * 262144;
    float(*tile)[65] = (float(*)[65])smem;
    int dr = t >> 2, ec = (t & 3) * 16;
#pragma unroll
    for (int j = 0; j < 16; j += 4) {
      float4 v = *(const float4*)&W[(long)(d0 + dr) * 512 + e0 + ec + j];
      tile[dr][ec + j] = v.x;
      tile[dr][ec + j + 1] = v.y;
      tile[dr][ec + j + 2] = v.z;
      tile[dr][ec + j + 3] = v.w;
    }
    __syncthreads();
    int er = t >> 2, dc = (t & 3) * 16;
    u16 tmp[16] __attribute__((aligned(16)));
#pragma unroll
    for (int j = 0; j < 16; ++j) tmp[j] = f2b(tile[dc + j][er]);
    *(short8*)&WT[(long)(e0 + er) * 512 + d0 + dc] = *(short8*)&tmp[0];
    *(short8*)&WT[(long)(e0 + er) * 512 + d0 + dc + 8] = *(short8*)&tmp[8];
  }
}

// ---------------------------------------------------------------------------
// generic bf16 GEMM  C[r][c] = sum_k A[r][k] * BT[c][k] + bias[c]
// ---------------------------------------------------------------------------
template <bool OBF>
__global__ __launch_bounds__(256) void gemm_bt(
    const u16* __restrict__ A, long sAz, int lda, const u16* __restrict__ BT,
    const float* __restrict__ bias, void* __restrict__ out, long sOz, int ldo) {
  __shared__ u16 As[128 * 32];
  __shared__ u16 Bs[128 * 32];
  const int z = blockIdx.z;
  const int tid = threadIdx.x, w = tid >> 6, l = tid & 63;
  const long row0 = (long)blockIdx.y * 128;
  const u16* Ab = A + (long)z * sAz + row0 * lda;
  const u16* Bb = BT + (long)z * 262144 + (long)blockIdx.x * 128 * 512;
  const u16* ga = Ab + (long)(w * 32 + (l >> 2)) * lda + (l & 3) * 8;
  const u16* gb = Bb + (long)(w * 32 + (l >> 2)) * 512 + (l & 3) * 8;
  u16* lA = As + w * 32 * 32;
  u16* lB = Bs + w * 32 * 32;
  f32x4 acc[4][4] = {};
  const int wr = (w >> 1) * 64, wc = (w & 1) * 64;
  for (int kt = 0; kt < 16; ++kt) {
    gload16(ga + kt * 32, lA);
    gload16(ga + kt * 32 + 16 * lda, lA + 16 * 32);
    gload16(gb + kt * 32, lB);
    gload16(gb + kt * 32 + 16 * 512, lB + 16 * 32);
    __syncthreads();
    short8 af[4], bf[4];
#pragma unroll
    for (int i = 0; i < 4; ++i)
      af[i] = *(const short8*)&As[(wr + i * 16 + (l & 15)) * 32 + (l >> 4) * 8];
#pragma unroll
    for (int i = 0; i < 4; ++i)
      bf[i] = *(const short8*)&Bs[(wc + i * 16 + (l & 15)) * 32 + (l >> 4) * 8];
#pragma unroll
    for (int i = 0; i < 4; ++i)
#pragma unroll
      for (int j = 0; j < 4; ++j) acc[i][j] = mfma16(af[i], bf[j], acc[i][j]);
    __syncthreads();
  }
  const int colB = blockIdx.x * 128 + wc;
#pragma unroll
  for (int i = 0; i < 4; ++i)
#pragma unroll
    for (int j = 0; j < 4; ++j) {
      int col = colB + j * 16 + (l & 15);
      float bb = bias[(long)z * 512 + col];
#pragma unroll
      for (int q = 0; q < 4; ++q) {
        long r = row0 + wr + i * 16 + (l >> 4) * 4 + q;
        float v = acc[i][j][q] + bb;
        if (OBF)
          ((u16*)out)[(long)z * sOz + r * ldo + col] = f2b(v);
        else
          ((float*)out)[(long)z * sOz + r * ldo + col] = v;
      }
    }
}

// ---------------------------------------------------------------------------
// fused QKV + V-transpose. block = (b*8+h, s-tile of 64, module m=z).
// ---------------------------------------------------------------------------
__global__ __launch_bounds__(256) void qkv_fused(
    const float* __restrict__ x, const float* __restrict__ EW,
    const u16* __restrict__ PB, u16* __restrict__ Q, u16* __restrict__ K,
    u16* __restrict__ VT, long mstride) {
  __shared__ float ews[3][4][64];
  __shared__ u16 vtile[64][72];
  const int bh = blockIdx.x;  // b*8+h
  const int st = blockIdx.y;
  const int m = blockIdx.z;
  const int b = bh >> 3, h = bh & 7;
  const int hoff = h * 64;
  const int t = threadIdx.x;
  if (t < 192) {
    int ty = t >> 6, dk = t & 63;
#pragma unroll
    for (int f = 0; f < 4; ++f)
      ews[ty][f][dk] = EW[(((long)(ty * 4 + m)) * 4 + f) * 512 + hoff + dk];
  }
  __syncthreads();
  const int sr = t >> 2, cq = t & 3;
  const int s = st * 64 + sr;
  const long rid = (long)b * 512 + s;
  const float* xr = x + rid * 7;
  const float xd = xr[3 + m], x0 = xr[0], x1 = xr[1], x2 = xr[2];
  const long obase = (long)m * mstride + rid * 512 + hoff + cq * 16;

  float res[3][16];
#pragma unroll
  for (int ty = 0; ty < 3; ++ty) {
    const u16* pbp =
        PB + (((long)(ty * 4 + m)) * 512 + s) * 512 + hoff + cq * 16;
    short8 pbv0 = *(const short8*)pbp;
    short8 pbv1 = *(const short8*)(pbp + 8);
#pragma unroll
    for (int j = 0; j < 16; ++j) {
      int dk = cq * 16 + j;
      u16 pb = (u16)(j < 8 ? pbv0[j] : pbv1[j - 8]);
      res[ty][j] = xd * ews[ty][0][dk] + x0 * ews[ty][1][dk] +
                   x1 * ews[ty][2][dk] + x2 * ews[ty][3][dk] + b2f(pb);
    }
  }
#pragma unroll
  for (int ty = 0; ty < 2; ++ty) {
    float ss = 0.f;
#pragma unroll
    for (int j = 0; j < 16; ++j) ss += res[ty][j] * res[ty][j];
    ss += __shfl_xor(ss, 1);
    ss += __shfl_xor(ss, 2);
    float sc = 1.f / fmaxf(sqrtf(ss), 1e-12f);
    u32 o[8];
#pragma unroll
    for (int jj = 0; jj < 8; ++jj)
      o[jj] = cvtpk(res[ty][2 * jj] * sc, res[ty][2 * jj + 1] * sc);
    u16* P = ty ? K : Q;
    *(u32x4*)&P[obase] = *(u32x4*)&o[0];
    *(u32x4*)&P[obase + 8] = *(u32x4*)&o[4];
  }
  {
    u32 o[8];
#pragma unroll
    for (int jj = 0; jj < 8; ++jj)
      o[jj] = cvtpk(res[2][2 * jj], res[2][2 * jj + 1]);
    *(short8*)&vtile[sr][cq * 16] = *(short8*)&o[0];
    *(short8*)&vtile[sr][cq * 16 + 8] = *(short8*)&o[4];
  }
  __syncthreads();
  {
    int kr = t >> 2, sc2 = (t & 3) * 16;
    u16 tmp[16] __attribute__((aligned(16)));
#pragma unroll
    for (int j = 0; j < 16; ++j) tmp[j] = vtile[sc2 + j][kr];
    long gdst = (long)m * mstride + ((long)bh * 64 + kr) * 512 + st * 64 + sc2;
    *(short8*)&VT[gdst] = *(short8*)&tmp[0];
    *(short8*)&VT[gdst + 8] = *(short8*)&tmp[8];
  }
}

// ---------------------------------------------------------------------------
// flash attention, max-free, 32x32 swapped-operand; 8-wave blocks (512 thr);
// counted vmcnt(2); P^T redistribution via v_permlane32_swap_b32 (bit-exact
// replacement of shfl_xor+cndmask, 4 ops instead of 16). ctx aliases Q.
// ---------------------------------------------------------------------------
__global__ __launch_bounds__(512, 4) void attn_kernel(
    const u16* Qg, const u16* __restrict__ Kg, const u16* __restrict__ VTg,
    u16* ctxg, long mstride) {
  __shared__ u16 Kb[2][64][64];
  __shared__ u16 Vb[2][64][64];
  const u16* Q = Qg + (long)blockIdx.z * mstride;
  const u16* K = Kg + (long)blockIdx.z * mstride;
  const u16* VT = VTg + (long)blockIdx.z * mstride;
  u16* ctx = ctxg + (long)blockIdx.z * mstride;
  const int bh = blockIdx.x;  // b*8+h
  const int qp = blockIdx.y;  // 0..1, 256 q-rows each
  const int b = bh >> 3, h = bh & 7;
  const int tid = threadIdx.x, w = tid >> 6, l = tid & 63;
  const int lq = l & 31, hi = l >> 5, l7 = l & 7;
  const long rowbase = (long)b * 512;
  const int hoff = h * 64;
  const int rw = l >> 3, gch = (l & 7) ^ rw;
  const int qrow = qp * 256 + w * 32;

  short8 qf[4];
  {
    const u16* qrp = Q + (rowbase + qrow + lq) * 512 + hoff + hi * 8;
#pragma unroll
    for (int dc = 0; dc < 4; ++dc) qf[dc] = *(const short8*)(qrp + dc * 16);
  }

  short8 ones;
#pragma unroll
  for (int i = 0; i < 8; ++i) ones[i] = (short)0x3F80;  // bf16 1.0

  f32x16 o_acc[2] = {};
  f32x16 l_acc = {};

  const u16* Kgbase = K + rowbase * 512 + hoff + gch * 8;
  const u16* Vgbase = VT + (long)bh * 64 * 512 + gch * 8;

  // 8 waves: wave w stages rows w*8..w*8+7 of the 64-row tile (2 loads/wave)
#define STAGE(bf, kt)                                                         \
  {                                                                           \
    int rr = w * 8;                                                           \
    gload16(Kgbase + (long)((kt)*64 + rr + rw) * 512, &Kb[bf][rr][0]);        \
    gload16(Vgbase + (long)(rr + rw) * 512 + (kt)*64, &Vb[bf][rr][0]);        \
  }

  STAGE(0, 0);  // 2 loads in flight

  for (int kt = 0; kt < 8; ++kt) {
    const int cur = kt & 1;
    if (kt < 7) {
      STAGE(cur ^ 1, kt + 1);  // issue next tile (2 more loads)
      asm volatile("s_waitcnt vmcnt(2)" ::: "memory");  // tile kt ready
    } else {
      asm volatile("s_waitcnt vmcnt(0)" ::: "memory");
    }
    __builtin_amdgcn_s_barrier();  // all waves' tile kt in LDS
    __builtin_amdgcn_sched_barrier(0);
    __builtin_amdgcn_s_setprio(1);
#pragma unroll
    for (int ktile = 0; ktile < 2; ++ktile) {
      f32x16 s = {};
#pragma unroll
      for (int dc = 0; dc < 4; ++dc) {
        short8 kf = *(const short8*)((const char*)&Kb[cur][ktile * 32 + lq][0] +
                                     (((dc * 2 + hi) ^ l7) * 16));
        s = mfma32(kf, qf[dc], s);
      }
      float p[16];
#pragma unroll
      for (int r = 0; r < 16; ++r) p[r] = __expf(s[r]);
      // pack pairs, then permlane32_swap: one swap yields both halves
      u32 s0a = cvtpk(p[0], p[1]), s0b = cvtpk(p[4], p[5]);
      u32 s1a = cvtpk(p[2], p[3]), s1b = cvtpk(p[6], p[7]);
      u32 s2a = cvtpk(p[8], p[9]), s2b = cvtpk(p[12], p[13]);
      u32 s3a = cvtpk(p[10], p[11]), s3b = cvtpk(p[14], p[15]);
      asm("v_permlane32_swap_b32 %0, %1" : "+v"(s0a), "+v"(s0b));
      asm("v_permlane32_swap_b32 %0, %1" : "+v"(s1a), "+v"(s1b));
      asm("v_permlane32_swap_b32 %0, %1" : "+v"(s2a), "+v"(s2b));
      asm("v_permlane32_swap_b32 %0, %1" : "+v"(s3a), "+v"(s3b));
      u32x4 f0v = {s0a, s1a, s0b, s1b};
      u32x4 f1v = {s2a, s3a, s2b, s3b};
      short8 bf0 = __builtin_bit_cast(short8, f0v);
      short8 bf1 = __builtin_bit_cast(short8, f1v);
#pragma unroll
      for (int kk2 = 0; kk2 < 2; ++kk2) {
        const int kc = ktile * 2 + kk2;
        short8 pb = kk2 ? bf1 : bf0;
        l_acc = mfma32(ones, pb, l_acc);  // row-sum on matrix pipe
#pragma unroll
        for (int dt = 0; dt < 2; ++dt) {
          short8 vf =
              *(const short8*)((const char*)&Vb[cur][dt * 32 + lq][0] +
                               (((kc * 2 + hi) ^ l7) * 16));
          o_acc[dt] = mfma32(vf, pb, o_acc[dt]);
        }
      }
    }
    __builtin_amdgcn_s_setprio(0);
    __builtin_amdgcn_sched_barrier(0);
    __builtin_amdgcn_s_barrier();  // all waves done reading cur (no drain)
    __builtin_amdgcn_sched_barrier(0);
  }
#undef STAGE
  const float inv = 1.f / l_acc[0];
  u16* crow = ctx + (rowbase + qrow + lq) * 512 + hoff + hi * 4;
#pragma unroll
  for (int dt = 0; dt < 2; ++dt)
#pragma unroll
    for (int rq = 0; rq < 4; ++rq) {
      u32 w0 = cvtpk(o_acc[dt][rq * 4 + 0] * inv, o_acc[dt][rq * 4 + 1] * inv);
      u32 w1 = cvtpk(o_acc[dt][rq * 4 + 2] * inv, o_acc[dt][rq * 4 + 3] * inv);
      u32x2 pr = {w0, w1};
      *(u32x2*)&crow[dt * 32 + rq * 8] = pr;
    }
}

// ---------------------------------------------------------------------------
// t[r][j] = sum_m ctx_m[r][:] . WEFFT[m][j][:]
// ---------------------------------------------------------------------------
__global__ __launch_bounds__(64) void t_gemm(const u16* __restrict__ ctx4,
                                             const u16* __restrict__ WEFFT,
                                             float* __restrict__ t) {
  const int l = threadIdx.x;
  const long r0 = (long)blockIdx.x * 16;
  f32x4 acc = {};
#pragma unroll
  for (int m = 0; m < 4; ++m) {
    const u16* A =
        ctx4 + (long)m * 8388608 + (r0 + (l & 15)) * 512 + (l >> 4) * 8;
    const u16* Bb = WEFFT + m * 8192 + (l & 15) * 512 + (l >> 4) * 8;
#pragma unroll
    for (int kt = 0; kt < 16; ++kt) {
      short8 af = *(const short8*)(A + kt * 32);
      short8 bf = *(const short8*)(Bb + kt * 32);
      acc = mfma16(af, bf, acc);
    }
  }
#pragma unroll
  for (int q = 0; q < 4; ++q)
    t[(r0 + (l >> 4) * 4 + q) * 16 + (l & 15)] = acc[q];
}

// ---------------------------------------------------------------------------
// tail_fused: c1 + conv2 + pool + fc1/fc2/fc3 + LN — one block per batch
// (512 threads; split-K partials for fc1/fc2)
// ---------------------------------------------------------------------------
__global__ __launch_bounds__(512) void tail_fused(
    const float* __restrict__ t, const float* __restrict__ bias_t,
    const float* __restrict__ b1, const float* __restrict__ w2,
    const float* __restrict__ b2, const float* __restrict__ fw1,
    const float* __restrict__ fb1, const float* __restrict__ fw2,
    const float* __restrict__ fb2, const float* __restrict__ fw3,
    const float* __restrict__ fb3, const float* __restrict__ g,
    const float* __restrict__ be, float* __restrict__ out) {
  __shared__ float ts[512][16];
  __shared__ float c1s[5][512];
  __shared__ float flat[512];
  __shared__ float z1p[2][256];
  __shared__ float z1[256];
  __shared__ float z2p[2][128];
  __shared__ float z2[128];
  __shared__ float z3[96];
  int b = blockIdx.x, tid = threadIdx.x;
  const float4* tsrc = (const float4*)(t + (long)b * 8192);
  float4* tdst = (float4*)&ts[0][0];
#pragma unroll
  for (int i = 0; i < 4; ++i) tdst[tid + i * 512] = tsrc[tid + i * 512];
  __syncthreads();
#pragma unroll
  for (int i = 0; i < 5; ++i) {
    int idx = tid + i * 512;  // 0..2559
    int o = idx >> 9, s = idx & 511;
    float a = b1[o];
#pragma unroll
    for (int k = 0; k < 3; ++k) {
      int ss = s + k - 1;
      if (ss >= 0 && ss < 512) a += ts[ss][o * 3 + k] + bias_t[o * 3 + k];
    }
    c1s[o][s] = eluf(a);
  }
  __syncthreads();
  {
    int r = tid;  // 0..511
    int o = r >> 8, sp = r & 255;
    float mx = -1e30f;
#pragma unroll
    for (int sd = 0; sd < 2; ++sd) {
      int s = sp * 2 + sd;
      float a = b2[o];
#pragma unroll
      for (int ic = 0; ic < 5; ++ic)
#pragma unroll
        for (int k = 0; k < 3; ++k) {
          int ss = s + k - 1;
          if (ss >= 0 && ss < 512) a += c1s[ic][ss] * w2[(o * 5 + ic) * 3 + k];
        }
      mx = fmaxf(mx, eluf(a));
    }
    flat[r] = mx;
  }
  __syncthreads();
  {
    int o = tid & 255, part = tid >> 8;
    float a = 0.f;
    const float* wp = fw1 + (long)part * 256 * 256 + o;
    const float* xp = flat + part * 256;
#pragma unroll 8
    for (int i = 0; i < 256; ++i) a += xp[i] * wp[i * 256];
    z1p[part][o] = a;
  }
  __syncthreads();
  if (tid < 256) z1[tid] = eluf(fb1[tid] + z1p[0][tid] + z1p[1][tid]);
  __syncthreads();
  if (tid < 256) {
    int o = tid & 127, part = tid >> 7;
    float a = 0.f;
    const float* wp = fw2 + (long)part * 128 * 128 + o;
    const float* xp = z1 + part * 128;
#pragma unroll 8
    for (int i = 0; i < 128; ++i) a += xp[i] * wp[i * 128];
    z2p[part][o] = a;
  }
  __syncthreads();
  if (tid < 128) z2[tid] = eluf(fb2[tid] + z2p[0][tid] + z2p[1][tid]);
  __syncthreads();
  if (tid < 96) {
    float a = fb3[tid];
#pragma unroll 8
    for (int i = 0; i < 128; ++i) a += z2[i] * fw3[i * 96 + tid];
    z3[tid] = a;
  }
  __syncthreads();
  if (tid < 96) {
    float mu = 0.f;
    for (int j = 0; j < 96; ++j) mu += z3[j];
    mu *= (1.f / 96.f);
    float sq = 0.f;
    for (int j = 0; j < 96; ++j) {
      float d = z3[j] - mu;
      sq += d * d;
    }
    float var = sq * (1.f / 96.f);
    out[b * 96 + tid] = (z3[tid] - mu) / sqrtf(var + 1e-5f) * g[tid] + be[tid];
  }
}

// ---------------------------------------------------------------------------
extern "C" void kernel_launch(void* const* d_in, const int* in_sizes, int n_in,
                              void* d_out, int out_size, void* d_ws,
                              size_t ws_size, hipStream_t stream) {
  (void)in_sizes; (void)n_in; (void)out_size;
  const float* x    = (const float*)d_in[0];
  const float* embW = (const float*)d_in[1];
  const float* embB = (const float*)d_in[2];
  const float* Wq   = (const float*)d_in[3];
  const float* bq   = (const float*)d_in[4];
  const float* Wk   = (const float*)d_in[5];
  const float* bk   = (const float*)d_in[6];
  const float* Wv   = (const float*)d_in[7];
  const float* bv   = (const float*)d_in[8];
  const float* Wo   = (const float*)d_in[9];
  const float* bo   = (const float*)d_in[10];
  const float* c1w  = (const float*)d_in[11];
  const float* c1b  = (const float*)d_in[12];
  const float* c2w  = (const float*)d_in[13];
  const float* c2b  = (const float*)d_in[14];
  const float* f1w  = (const float*)d_in[15];
  const float* f1b  = (const float*)d_in[16];
  const float* f2w  = (const float*)d_in[17];
  const float* f2b_ = (const float*)d_in[18];
  const float* f3w  = (const float*)d_in[19];
  const float* f3b  = (const float*)d_in[20];
  const float* lng  = (const float*)d_in[21];
  const float* lnb  = (const float*)d_in[22];
  float* out = (float*)d_out;

  char* p = (char*)d_ws;
  const size_t NEED = 215736384;
  if (ws_size < NEED) return;
  const long MS = 8388608;  // per-module stride in u16 elements (16 MB)

  u16*   A_pe    = (u16*)(p + 0);
  u16*   WTqkv   = (u16*)(p + 524288);
  float* pb_bias = (float*)(p + 6815744);
  float* EW      = (float*)(p + 6840320);
  u16*   PB      = (u16*)(p + 6938624);
  u16*   Q4      = (u16*)(p + 13230080);   // 4 x 16.77 MB ; ctx4 aliases this
  u16*   K4      = (u16*)(p + 80338944);
  u16*   VT4     = (u16*)(p + 147447808);
  u16*   ctx4    = Q4;                     // attn writes ctx over its own Q
  u16*   WEFFT   = (u16*)(p + 214556672);
  float* bias_t  = (float*)(p + 214622208);
  float* t_buf   = (float*)(p + 214622272);

  prep_misc<<<1829, 256, 0, stream>>>(embB, bq, bk, bv, Wq, Wk, Wv, embW, Wo,
                                      bo, c1w, A_pe, pb_bias, EW, WEFFT,
                                      bias_t, WTqkv);
  gemm_bt<true><<<dim3(4, 4, 12), 256, 0, stream>>>(
      A_pe, 0, 512, WTqkv, pb_bias, (void*)PB, 262144, 512);

  qkv_fused<<<dim3(256, 8, 4), 256, 0, stream>>>(x, EW, PB, Q4, K4, VT4, MS);
  attn_kernel<<<dim3(256, 2, 4), 512, 0, stream>>>(Q4, K4, VT4, ctx4, MS);

  t_gemm<<<1024, 64, 0, stream>>>(ctx4, WEFFT, t_buf);
  tail_fused<<<32, 512, 0, stream>>>(t_buf, bias_t, c1b, c2w, c2b, f1w, f1b,
                                     f2w, f2b_, f3w, f3b, lng, lnb, out);
}